// Round 10
// baseline (810.744 us; speedup 1.0000x reference)
//
#include <hip/hip_runtime.h>
#include <hip/hip_fp16.h>
#include <cstdint>
#include <cstddef>

#define BB 128
#define SS 256
#define LL 10
#define NTAGS 32
#define TAG_START 30
#define TAG_END 31
#define WDIM 100
#define CDIM 30
#define NFILT 30
#define HDIM 100
#define KIN 130      // LSTM_IN = WDIM + FILT
#define GDIM 400     // 4*H
#define NEGV -10000.0f
#define CTOK 8       // tokens per charconv block

typedef _Float16 h2 __attribute__((ext_vector_type(2)));
typedef _Float16 f16x8 __attribute__((ext_vector_type(8)));
typedef float f32x4 __attribute__((ext_vector_type(4)));

__device__ __forceinline__ float sigm(float x) { return 1.0f / (1.0f + __expf(-x)); }
__device__ __forceinline__ float tanh_fast(float x) { return 2.0f / (1.0f + __expf(-2.0f * x)) - 1.0f; }

// ---------------- K1a: word embedding gather -> x[:, 0:100] ----------------
__global__ void k_word(const float* __restrict__ wemb, const int* __restrict__ wx,
                       float* __restrict__ x) {
  int idx = blockIdx.x * blockDim.x + threadIdx.x;
  if (idx >= BB * SS * WDIM) return;
  int token = idx / WDIM;
  int d = idx - token * WDIM;
  x[(size_t)token * KIN + d] = wemb[(size_t)wx[token] * WDIM + d];
}

// ---------------- K1b: char conv + max-pool -> x[:, 100:130] ----------------
__global__ __launch_bounds__(256) void k_charconv(const float* __restrict__ cemb,
                                                  const float* __restrict__ convw,
                                                  const float* __restrict__ convb,
                                                  const int* __restrict__ cx,
                                                  float* __restrict__ x) {
  int blk = blockIdx.x;
  int tid = threadIdx.x;
  int tok8 = tid >> 5;
  int f = tid & 31;
  int token0 = blk * CTOK;
  __shared__ float e[CTOK][LL * CDIM];
  __shared__ int ci[CTOK][LL];
  if (tid < CTOK * LL) {
    int t = tid / LL, l = tid - t * LL;
    ci[t][l] = cx[(token0 + t) * LL + l];
  }
  __syncthreads();
  for (int i = tid; i < CTOK * LL * CDIM; i += 256) {
    int t = i / (LL * CDIM);
    int r = i - t * (LL * CDIM);
    int l = r / CDIM, c = r - l * CDIM;
    e[t][l * CDIM + c] = cemb[ci[t][l] * CDIM + c];
  }
  __syncthreads();
  if (f < NFILT) {
    float d0[LL], d1[LL], d2[LL];
#pragma unroll
    for (int l = 0; l < LL; l++) { d0[l] = 0.f; d1[l] = 0.f; d2[l] = 0.f; }
    const float* et = &e[tok8][0];
    for (int c = 0; c < CDIM; c++) {
      float w0 = convw[(f * 3 + 0) * CDIM + c];
      float w1 = convw[(f * 3 + 1) * CDIM + c];
      float w2 = convw[(f * 3 + 2) * CDIM + c];
#pragma unroll
      for (int l = 0; l < LL; l++) {
        float ev = et[l * CDIM + c];
        d0[l] += ev * w0; d1[l] += ev * w1; d2[l] += ev * w2;
      }
    }
    float bias = convb[f];
    float m = -3.0e38f;
#pragma unroll
    for (int h = 0; h < LL + 2; h++) {
      float acc = bias;
      int j0 = h - 2, j1 = h - 1, j2 = h;
      if (j0 >= 0 && j0 < LL) acc += d0[j0];
      if (j1 >= 0 && j1 < LL) acc += d1[j1];
      if (j2 >= 0 && j2 < LL) acc += d2[j2];
      m = fmaxf(m, acc);
    }
    x[(size_t)(token0 + tok8) * KIN + WDIM + f] = m;
  }
}

// ---------------- K2: pre = x @ wih^T + (bih+bhh), MFMA f16 ----------------
// C(32768 x 800) = x(32768 x 130) @ W^T, W rows 0..399 = wih_f, 400..799 = wih_b.
// mfma_f32_16x16x32_f16, HW-verified layouts (m89/m91/m120):
//   A: lane holds A[m=lane&15][k=(lane>>4)*8 + j], j=0..7
//   B: lane holds B[k=(lane>>4)*8 + j][n=lane&15]
//   C/D: col=lane&15, row=(lane>>4)*4 + reg
// Block tile 64x64, K padded to 160 (5 chunks of 32, zeros past 130).
// 4 waves: wave w owns N-subtile w (16 cols) x all 4 M-subtiles.
// LDS [row][k] stride 40 halves (80 B) -> <=2-way bank aliasing (free).
__global__ __launch_bounds__(256) void k_pregemm(
    const float* __restrict__ x,
    const float* __restrict__ wihF, const float* __restrict__ wihB,
    const float* __restrict__ bihF, const float* __restrict__ bhhF,
    const float* __restrict__ bihB, const float* __restrict__ bhhB,
    float* __restrict__ preF, float* __restrict__ preB) {
  __shared__ __align__(16) _Float16 Asl[64 * 40];
  __shared__ __align__(16) _Float16 Bsl[64 * 40];
  int m0 = blockIdx.x * 64;
  int n0 = blockIdx.y * 64;
  int tid = threadIdx.x;
  int lane = tid & 63, w = tid >> 6;
  int quad = lane >> 4, l15 = lane & 15;

  f32x4 acc[4];
#pragma unroll
  for (int i = 0; i < 4; i++) acc[i] = (f32x4){0.f, 0.f, 0.f, 0.f};

  int r = tid >> 2;            // staging row 0..63
  int kk = (tid & 3) * 8;      // k offset within chunk
  int ngs = n0 + r;            // B staging source row
  const float* wrs = (ngs < GDIM) ? (wihF + (size_t)ngs * KIN)
                    : (ngs < 2 * GDIM) ? (wihB + (size_t)(ngs - GDIM) * KIN) : nullptr;
  const float* xrs = x + (size_t)(m0 + r) * KIN;

  for (int kc = 0; kc < 5; kc++) {
    if (kc) __syncthreads();
    int kg0 = kc * 32 + kk;
    f16x8 ta, tb;
#pragma unroll
    for (int q = 0; q < 8; q++) {
      int kg = kg0 + q;
      ta[q] = (_Float16)(kg < KIN ? xrs[kg] : 0.f);
      tb[q] = (_Float16)((wrs && kg < KIN) ? wrs[kg] : 0.f);
    }
    *(f16x8*)&Asl[r * 40 + kk] = ta;
    *(f16x8*)&Bsl[r * 40 + kk] = tb;
    __syncthreads();

    f16x8 bfrag = *(const f16x8*)&Bsl[(w * 16 + l15) * 40 + quad * 8];
#pragma unroll
    for (int mt = 0; mt < 4; mt++) {
      f16x8 afrag = *(const f16x8*)&Asl[(mt * 16 + l15) * 40 + quad * 8];
      acc[mt] = __builtin_amdgcn_mfma_f32_16x16x32_f16(afrag, bfrag, acc[mt], 0, 0, 0);
    }
  }

  int ng = n0 + w * 16 + l15;  // this lane's output column (fixed)
  if (ng < 2 * GDIM) {
    int dir = ng >= GDIM;
    int jb = dir ? ng - GDIM : ng;
    float* dst = dir ? preB : preF;
    float bias = (dir ? bihB : bihF)[jb] + (dir ? bhhB : bhhF)[jb];
#pragma unroll
    for (int mt = 0; mt < 4; mt++) {
#pragma unroll
      for (int i = 0; i < 4; i++) {
        int m = m0 + mt * 16 + quad * 4 + i;
        dst[(size_t)m * GDIM + jb] = acc[mt][i] + bias;
      }
    }
  }
}

// ---------------- K3: recurrent LSTM scan, block per (batch, dir) ----------------
// BYTE-IDENTICAL to round-8's passing kernel (absmax 0.0, 255 us).
__global__ __launch_bounds__(512) void k_lstm(
    const float* __restrict__ preF, const float* __restrict__ preB,
    const float* __restrict__ whhF, const float* __restrict__ whhB,
    float* __restrict__ hbuf) {
  int blk = blockIdx.x;
  int dir = blk >> 7;   // 0 fwd, 1 bwd
  int b = blk & 127;
  const float* pre = dir ? preB : preF;
  const float* whh = dir ? whhB : whhF;
  int j = threadIdx.x;
  bool act = (j < GDIM);
  int jc = act ? j : (GDIM - 1);

  h2 wp[52];   // 104 f16 weights (last 4 zero) = 52 VGPRs
  {
    const float2* w2 = (const float2*)(whh + (size_t)jc * HDIM);
#pragma unroll
    for (int k = 0; k < 50; k++) {
      float2 w = w2[k];
      h2 hw; hw.x = (_Float16)w.x; hw.y = (_Float16)w.y;
      wp[k] = hw;
    }
    h2 z; z.x = (_Float16)0.f; z.y = (_Float16)0.f;
    wp[50] = z; wp[51] = z;
  }

  __shared__ __align__(16) _Float16 hsh16[2][104];
  __shared__ float gsh[GDIM];
  if (j < 104) { hsh16[0][j] = (_Float16)0.f; hsh16[1][j] = (_Float16)0.f; }
  float c = 0.f;

  const float* pbase = pre + ((size_t)b * SS + (dir ? (SS - 1) : 0)) * GDIM + jc;
  const intptr_t pstep = dir ? -(intptr_t)GDIM : (intptr_t)GDIM;

  float p0 = pbase[0];
  float p1 = pbase[pstep];
  __syncthreads();

  int cur = 0;
  for (int step = 0; step < SS; step++) {
    int tn = (step + 2 < SS) ? (step + 2) : (SS - 1);
    float p2 = pbase[(intptr_t)tn * pstep];

    {
      const uint4* h4 = (const uint4*)&hsh16[cur][0];
      float acc = p0;  // sequential chain
#pragma unroll
      for (int kk = 0; kk < 13; kk++) {
        uint4 hv = h4[kk];
        h2 ha = __builtin_bit_cast(h2, hv.x);
        h2 hb = __builtin_bit_cast(h2, hv.y);
        h2 hc = __builtin_bit_cast(h2, hv.z);
        h2 hd = __builtin_bit_cast(h2, hv.w);
        h2 wa = wp[4 * kk], wb = wp[4 * kk + 1];
        h2 wc = wp[4 * kk + 2], wd = wp[4 * kk + 3];
        acc = fmaf((float)ha.x, (float)wa.x, acc);
        acc = fmaf((float)ha.y, (float)wa.y, acc);
        acc = fmaf((float)hb.x, (float)wb.x, acc);
        acc = fmaf((float)hb.y, (float)wb.y, acc);
        acc = fmaf((float)hc.x, (float)wc.x, acc);
        acc = fmaf((float)hc.y, (float)wc.y, acc);
        acc = fmaf((float)hd.x, (float)wd.x, acc);
        acc = fmaf((float)hd.y, (float)wd.y, acc);
      }
      if (act) gsh[j] = acc;
    }
    __syncthreads();
    if (j < HDIM) {
      float ig = sigm(gsh[j]);
      float fg = sigm(gsh[j + HDIM]);
      float gg = tanh_fast(gsh[j + 2 * HDIM]);
      float og = sigm(gsh[j + 3 * HDIM]);
      c = fg * c + ig * gg;
      float h = og * tanh_fast(c);
      hsh16[cur ^ 1][j] = (_Float16)h;
      int t = dir ? (SS - 1 - step) : step;
      hbuf[((size_t)b * SS + t) * (2 * HDIM) + dir * HDIM + j] = h;
    }
    __syncthreads();
    p0 = p1; p1 = p2;
    cur ^= 1;
  }
}

// ---------------- K4: emission = [h_f,h_b] @ proj_w^T + proj_b ----------------
__global__ void k_proj(const float* __restrict__ hbuf, const float* __restrict__ pw,
                       const float* __restrict__ pb, float* __restrict__ em) {
  int idx = blockIdx.x * blockDim.x + threadIdx.x;  // token*32 + tag
  if (idx >= BB * SS * NTAGS) return;
  int token = idx >> 5, tag = idx & 31;
  const float4* h4 = (const float4*)(hbuf + (size_t)token * 2 * HDIM);
  const float4* w4 = (const float4*)(pw + (size_t)tag * 2 * HDIM);
  float acc = pb[tag];
#pragma unroll 10
  for (int k = 0; k < 50; k++) {
    float4 hv = h4[k], wv = w4[k];
    acc += hv.x * wv.x + hv.y * wv.y + hv.z * wv.z + hv.w * wv.w;
  }
  em[idx] = acc;
}

// ---------------- K5: gold path score per batch ----------------
__global__ __launch_bounds__(64) void k_score(const float* __restrict__ em,
                                              const float* __restrict__ trans,
                                              const int* __restrict__ y,
                                              const int* __restrict__ mask,
                                              float* __restrict__ scoreY) {
  int b = blockIdx.x, l = threadIdx.x;
  float acc = 0.f;
  for (int s = l; s < SS; s += 64) {
    int curt = y[b * SS + s];
    int prevt = (s == 0) ? TAG_START : y[b * SS + s - 1];
    float mk = (float)mask[b * SS + s];
    acc += (em[((size_t)b * SS + s) * NTAGS + curt] + trans[prevt * NTAGS + curt]) * mk;
  }
#pragma unroll
  for (int off = 32; off > 0; off >>= 1) acc += __shfl_down(acc, off);
  if (l == 0) scoreY[b] = acc + trans[y[b * SS + SS - 1] * NTAGS + TAG_END];
}

// ---------------- K6: CRF forward (partition function) + loss ----------------
__global__ __launch_bounds__(64) void k_crf(const float* __restrict__ em,
                                            const float* __restrict__ trans,
                                            const int* __restrict__ mask,
                                            const float* __restrict__ scoreY,
                                            float* __restrict__ out) {
  int g = threadIdx.x >> 5;
  int j = threadIdx.x & 31;
  int b = blockIdx.x * 2 + g;
  float tcol[NTAGS];
#pragma unroll
  for (int i = 0; i < NTAGS; i++) tcol[i] = trans[i * NTAGS + j];
  float la = (j == TAG_START) ? 0.f : NEGV;
  __shared__ float lash[2][NTAGS];
  for (int s = 0; s < SS; s++) {
    lash[g][j] = la;
    __syncthreads();
    float emv = em[((size_t)b * SS + s) * NTAGS + j];
    float m = -3.0e38f;
#pragma unroll
    for (int i = 0; i < NTAGS; i++) m = fmaxf(m, lash[g][i] + tcol[i]);
    float sum = 0.f;
#pragma unroll
    for (int i = 0; i < NTAGS; i++) sum += __expf(lash[g][i] + tcol[i] - m);
    float la2 = m + __logf(sum) + emv;
    float mk = (float)mask[b * SS + s];
    la = la2 * mk + la * (1.f - mk);
    __syncthreads();
  }
  la += trans[j * NTAGS + TAG_END];
  lash[g][j] = la;
  __syncthreads();
  float m = -3.0e38f;
#pragma unroll
  for (int i = 0; i < NTAGS; i++) m = fmaxf(m, lash[g][i]);
  float sum = 0.f;
#pragma unroll
  for (int i = 0; i < NTAGS; i++) sum += __expf(lash[g][i] - m);
  float total = m + __logf(sum);
  if (j == 0) atomicAdd(out, (total - scoreY[b]) * (1.0f / BB));
}

extern "C" void kernel_launch(void* const* d_in, const int* in_sizes, int n_in,
                              void* d_out, int out_size, void* d_ws, size_t ws_size,
                              hipStream_t stream) {
  const float* word_emb = (const float*)d_in[0];
  const float* char_emb = (const float*)d_in[1];
  const float* conv_w   = (const float*)d_in[2];
  const float* conv_b   = (const float*)d_in[3];
  const float* wih_f    = (const float*)d_in[4];
  const float* whh_f    = (const float*)d_in[5];
  const float* bih_f    = (const float*)d_in[6];
  const float* bhh_f    = (const float*)d_in[7];
  const float* wih_b    = (const float*)d_in[8];
  const float* whh_b    = (const float*)d_in[9];
  const float* bih_b    = (const float*)d_in[10];
  const float* bhh_b    = (const float*)d_in[11];
  const float* proj_w   = (const float*)d_in[12];
  const float* proj_b   = (const float*)d_in[13];
  const float* trans    = (const float*)d_in[14];
  const int* word_x     = (const int*)d_in[15];
  const int* char_x     = (const int*)d_in[16];
  const int* y          = (const int*)d_in[17];
  const int* mask       = (const int*)d_in[18];
  float* out = (float*)d_out;

  float* ws = (float*)d_ws;
  float* x      = ws;                                  // 32768*130
  float* preF   = x + (size_t)BB * SS * KIN;           // 32768*400
  float* preB   = preF + (size_t)BB * SS * GDIM;       // 32768*400
  float* hbuf   = preB + (size_t)BB * SS * GDIM;       // 32768*200
  float* em     = hbuf + (size_t)BB * SS * 2 * HDIM;   // 32768*32
  float* scoreY = em + (size_t)BB * SS * NTAGS;        // 128

  hipMemsetAsync(d_out, 0, sizeof(float), stream);
  k_word<<<(BB * SS * WDIM + 255) / 256, 256, 0, stream>>>(word_emb, word_x, x);
  k_charconv<<<BB * SS / CTOK, 256, 0, stream>>>(char_emb, conv_w, conv_b, char_x, x);
  k_pregemm<<<dim3(BB * SS / 64, 13), 256, 0, stream>>>(x, wih_f, wih_b, bih_f, bhh_f,
                                                        bih_b, bhh_b, preF, preB);
  k_lstm<<<256, 512, 0, stream>>>(preF, preB, whh_f, whh_b, hbuf);
  k_proj<<<(BB * SS * NTAGS + 255) / 256, 256, 0, stream>>>(hbuf, proj_w, proj_b, em);
  k_score<<<BB, 64, 0, stream>>>(em, trans, y, mask, scoreY);
  k_crf<<<BB / 2, 64, 0, stream>>>(em, trans, mask, scoreY, out);
}

// Round 11
// 669.204 us; speedup vs baseline: 1.2115x; 1.2115x over previous
//
#include <hip/hip_runtime.h>
#include <hip/hip_fp16.h>
#include <cstdint>
#include <cstddef>

#define BB 128
#define SS 256
#define LL 10
#define NTAGS 32
#define TAG_START 30
#define TAG_END 31
#define WDIM 100
#define CDIM 30
#define NFILT 30
#define HDIM 100
#define KIN 130      // LSTM_IN = WDIM + FILT
#define KPAD 160     // padded K for f16 GEMM operands
#define GDIM 400     // 4*H
#define NROWS 832    // 13*64 padded W rows
#define NEGV -10000.0f
#define CTOK 8       // tokens per charconv block

typedef _Float16 h2 __attribute__((ext_vector_type(2)));
typedef _Float16 f16x8 __attribute__((ext_vector_type(8)));
typedef float f32x4 __attribute__((ext_vector_type(4)));

__device__ __forceinline__ float sigm(float x) { return 1.0f / (1.0f + __expf(-x)); }
__device__ __forceinline__ float tanh_fast(float x) { return 2.0f / (1.0f + __expf(-2.0f * x)) - 1.0f; }

// ---------------- K1a: word embedding gather -> x16[:, 0:100], zero pad [130:160) ----------------
__global__ void k_word(const float* __restrict__ wemb, const int* __restrict__ wx,
                       _Float16* __restrict__ x16) {
  int idx = blockIdx.x * blockDim.x + threadIdx.x;
  if (idx >= BB * SS * KPAD) return;
  int token = idx / KPAD;
  int d = idx - token * KPAD;
  if (d < WDIM) {
    x16[idx] = (_Float16)wemb[(size_t)wx[token] * WDIM + d];
  } else if (d >= KIN) {
    x16[idx] = (_Float16)0.f;
  }
  // d in [100,130): written by k_charconv
}

// ---------------- K1b: char conv + max-pool -> x16[:, 100:130] ----------------
__global__ __launch_bounds__(256) void k_charconv(const float* __restrict__ cemb,
                                                  const float* __restrict__ convw,
                                                  const float* __restrict__ convb,
                                                  const int* __restrict__ cx,
                                                  _Float16* __restrict__ x16) {
  int blk = blockIdx.x;
  int tid = threadIdx.x;
  int tok8 = tid >> 5;
  int f = tid & 31;
  int token0 = blk * CTOK;
  __shared__ float e[CTOK][LL * CDIM];
  __shared__ int ci[CTOK][LL];
  if (tid < CTOK * LL) {
    int t = tid / LL, l = tid - t * LL;
    ci[t][l] = cx[(token0 + t) * LL + l];
  }
  __syncthreads();
  for (int i = tid; i < CTOK * LL * CDIM; i += 256) {
    int t = i / (LL * CDIM);
    int r = i - t * (LL * CDIM);
    int l = r / CDIM, c = r - l * CDIM;
    e[t][l * CDIM + c] = cemb[ci[t][l] * CDIM + c];
  }
  __syncthreads();
  if (f < NFILT) {
    float d0[LL], d1[LL], d2[LL];
#pragma unroll
    for (int l = 0; l < LL; l++) { d0[l] = 0.f; d1[l] = 0.f; d2[l] = 0.f; }
    const float* et = &e[tok8][0];
    for (int c = 0; c < CDIM; c++) {
      float w0 = convw[(f * 3 + 0) * CDIM + c];
      float w1 = convw[(f * 3 + 1) * CDIM + c];
      float w2 = convw[(f * 3 + 2) * CDIM + c];
#pragma unroll
      for (int l = 0; l < LL; l++) {
        float ev = et[l * CDIM + c];
        d0[l] += ev * w0; d1[l] += ev * w1; d2[l] += ev * w2;
      }
    }
    float bias = convb[f];
    float m = -3.0e38f;
#pragma unroll
    for (int h = 0; h < LL + 2; h++) {
      float acc = bias;
      int j0 = h - 2, j1 = h - 1, j2 = h;
      if (j0 >= 0 && j0 < LL) acc += d0[j0];
      if (j1 >= 0 && j1 < LL) acc += d1[j1];
      if (j2 >= 0 && j2 < LL) acc += d2[j2];
      m = fmaxf(m, acc);
    }
    x16[(size_t)(token0 + tok8) * KPAD + WDIM + f] = (_Float16)m;
  }
}

// ---------------- K1c: W (wih_f | wih_b) -> f16 [832][160], padded zeros ----------------
__global__ void k_wcvt(const float* __restrict__ wihF, const float* __restrict__ wihB,
                       _Float16* __restrict__ w16) {
  int idx = blockIdx.x * blockDim.x + threadIdx.x;
  if (idx >= NROWS * KPAD) return;
  int n = idx / KPAD;
  int k = idx - n * KPAD;
  float v = 0.f;
  if (k < KIN && n < 2 * GDIM) {
    v = (n < GDIM) ? wihF[(size_t)n * KIN + k] : wihB[(size_t)(n - GDIM) * KIN + k];
  }
  w16[idx] = (_Float16)v;
}

// ---------------- K2: pre = x @ wih^T + (bih+bhh), MFMA f16 ----------------
// Same MFMA structure as R10 (verified absmax 0.0); staging now pure 16B
// copies from pre-converted f16 operands (R10's 80 guarded scalar loads +
// converts per thread were the regression).
__global__ __launch_bounds__(256) void k_pregemm(
    const _Float16* __restrict__ x16, const _Float16* __restrict__ w16,
    const float* __restrict__ bihF, const float* __restrict__ bhhF,
    const float* __restrict__ bihB, const float* __restrict__ bhhB,
    float* __restrict__ preF, float* __restrict__ preB) {
  __shared__ __align__(16) _Float16 Asl[64 * 40];
  __shared__ __align__(16) _Float16 Bsl[64 * 40];
  int m0 = blockIdx.x * 64;
  int n0 = blockIdx.y * 64;
  int tid = threadIdx.x;
  int lane = tid & 63, w = tid >> 6;
  int quad = lane >> 4, l15 = lane & 15;

  f32x4 acc[4];
#pragma unroll
  for (int i = 0; i < 4; i++) acc[i] = (f32x4){0.f, 0.f, 0.f, 0.f};

  int r = tid >> 2;            // staging row 0..63
  int kk = (tid & 3) * 8;      // k offset within chunk
  const _Float16* xs = x16 + (size_t)(m0 + r) * KPAD + kk;
  const _Float16* wsrc = w16 + (size_t)(n0 + r) * KPAD + kk;

  for (int kc = 0; kc < 5; kc++) {
    if (kc) __syncthreads();
    *(f16x8*)&Asl[r * 40 + kk] = *(const f16x8*)(xs + kc * 32);
    *(f16x8*)&Bsl[r * 40 + kk] = *(const f16x8*)(wsrc + kc * 32);
    __syncthreads();

    f16x8 bfrag = *(const f16x8*)&Bsl[(w * 16 + l15) * 40 + quad * 8];
#pragma unroll
    for (int mt = 0; mt < 4; mt++) {
      f16x8 afrag = *(const f16x8*)&Asl[(mt * 16 + l15) * 40 + quad * 8];
      acc[mt] = __builtin_amdgcn_mfma_f32_16x16x32_f16(afrag, bfrag, acc[mt], 0, 0, 0);
    }
  }

  int ng = n0 + w * 16 + l15;  // this lane's output column (fixed)
  if (ng < 2 * GDIM) {
    int dir = ng >= GDIM;
    int jb = dir ? ng - GDIM : ng;
    float* dst = dir ? preB : preF;
    float bias = (dir ? bihB : bihF)[jb] + (dir ? bhhB : bhhF)[jb];
#pragma unroll
    for (int mt = 0; mt < 4; mt++) {
#pragma unroll
      for (int i = 0; i < 4; i++) {
        int m = m0 + mt * 16 + quad * 4 + i;
        dst[(size_t)m * GDIM + jb] = acc[mt][i] + bias;
      }
    }
  }
}

// ---------------- K3: recurrent LSTM scan, block per (batch, dir) ----------------
// BYTE-IDENTICAL to round-8's passing kernel (absmax 0.0, 255 us).
__global__ __launch_bounds__(512) void k_lstm(
    const float* __restrict__ preF, const float* __restrict__ preB,
    const float* __restrict__ whhF, const float* __restrict__ whhB,
    float* __restrict__ hbuf) {
  int blk = blockIdx.x;
  int dir = blk >> 7;   // 0 fwd, 1 bwd
  int b = blk & 127;
  const float* pre = dir ? preB : preF;
  const float* whh = dir ? whhB : whhF;
  int j = threadIdx.x;
  bool act = (j < GDIM);
  int jc = act ? j : (GDIM - 1);

  h2 wp[52];   // 104 f16 weights (last 4 zero) = 52 VGPRs
  {
    const float2* w2 = (const float2*)(whh + (size_t)jc * HDIM);
#pragma unroll
    for (int k = 0; k < 50; k++) {
      float2 w = w2[k];
      h2 hw; hw.x = (_Float16)w.x; hw.y = (_Float16)w.y;
      wp[k] = hw;
    }
    h2 z; z.x = (_Float16)0.f; z.y = (_Float16)0.f;
    wp[50] = z; wp[51] = z;
  }

  __shared__ __align__(16) _Float16 hsh16[2][104];
  __shared__ float gsh[GDIM];
  if (j < 104) { hsh16[0][j] = (_Float16)0.f; hsh16[1][j] = (_Float16)0.f; }
  float c = 0.f;

  const float* pbase = pre + ((size_t)b * SS + (dir ? (SS - 1) : 0)) * GDIM + jc;
  const intptr_t pstep = dir ? -(intptr_t)GDIM : (intptr_t)GDIM;

  float p0 = pbase[0];
  float p1 = pbase[pstep];
  __syncthreads();

  int cur = 0;
  for (int step = 0; step < SS; step++) {
    int tn = (step + 2 < SS) ? (step + 2) : (SS - 1);
    float p2 = pbase[(intptr_t)tn * pstep];

    {
      const uint4* h4 = (const uint4*)&hsh16[cur][0];
      float acc = p0;  // sequential chain
#pragma unroll
      for (int kk = 0; kk < 13; kk++) {
        uint4 hv = h4[kk];
        h2 ha = __builtin_bit_cast(h2, hv.x);
        h2 hb = __builtin_bit_cast(h2, hv.y);
        h2 hc = __builtin_bit_cast(h2, hv.z);
        h2 hd = __builtin_bit_cast(h2, hv.w);
        h2 wa = wp[4 * kk], wb = wp[4 * kk + 1];
        h2 wc = wp[4 * kk + 2], wd = wp[4 * kk + 3];
        acc = fmaf((float)ha.x, (float)wa.x, acc);
        acc = fmaf((float)ha.y, (float)wa.y, acc);
        acc = fmaf((float)hb.x, (float)wb.x, acc);
        acc = fmaf((float)hb.y, (float)wb.y, acc);
        acc = fmaf((float)hc.x, (float)wc.x, acc);
        acc = fmaf((float)hc.y, (float)wc.y, acc);
        acc = fmaf((float)hd.x, (float)wd.x, acc);
        acc = fmaf((float)hd.y, (float)wd.y, acc);
      }
      if (act) gsh[j] = acc;
    }
    __syncthreads();
    if (j < HDIM) {
      float ig = sigm(gsh[j]);
      float fg = sigm(gsh[j + HDIM]);
      float gg = tanh_fast(gsh[j + 2 * HDIM]);
      float og = sigm(gsh[j + 3 * HDIM]);
      c = fg * c + ig * gg;
      float h = og * tanh_fast(c);
      hsh16[cur ^ 1][j] = (_Float16)h;
      int t = dir ? (SS - 1 - step) : step;
      hbuf[((size_t)b * SS + t) * (2 * HDIM) + dir * HDIM + j] = h;
    }
    __syncthreads();
    p0 = p1; p1 = p2;
    cur ^= 1;
  }
}

// ---------------- K4: emission = [h_f,h_b] @ proj_w^T + proj_b ----------------
__global__ void k_proj(const float* __restrict__ hbuf, const float* __restrict__ pw,
                       const float* __restrict__ pb, float* __restrict__ em) {
  int idx = blockIdx.x * blockDim.x + threadIdx.x;  // token*32 + tag
  if (idx >= BB * SS * NTAGS) return;
  int token = idx >> 5, tag = idx & 31;
  const float4* h4 = (const float4*)(hbuf + (size_t)token * 2 * HDIM);
  const float4* w4 = (const float4*)(pw + (size_t)tag * 2 * HDIM);
  float acc = pb[tag];
#pragma unroll 10
  for (int k = 0; k < 50; k++) {
    float4 hv = h4[k], wv = w4[k];
    acc += hv.x * wv.x + hv.y * wv.y + hv.z * wv.z + hv.w * wv.w;
  }
  em[idx] = acc;
}

// ---------------- K5: gold path score per batch ----------------
__global__ __launch_bounds__(64) void k_score(const float* __restrict__ em,
                                              const float* __restrict__ trans,
                                              const int* __restrict__ y,
                                              const int* __restrict__ mask,
                                              float* __restrict__ scoreY) {
  int b = blockIdx.x, l = threadIdx.x;
  float acc = 0.f;
  for (int s = l; s < SS; s += 64) {
    int curt = y[b * SS + s];
    int prevt = (s == 0) ? TAG_START : y[b * SS + s - 1];
    float mk = (float)mask[b * SS + s];
    acc += (em[((size_t)b * SS + s) * NTAGS + curt] + trans[prevt * NTAGS + curt]) * mk;
  }
#pragma unroll
  for (int off = 32; off > 0; off >>= 1) acc += __shfl_down(acc, off);
  if (l == 0) scoreY[b] = acc + trans[y[b * SS + SS - 1] * NTAGS + TAG_END];
}

// ---------------- K6: CRF forward (partition function) + loss ----------------
__global__ __launch_bounds__(64) void k_crf(const float* __restrict__ em,
                                            const float* __restrict__ trans,
                                            const int* __restrict__ mask,
                                            const float* __restrict__ scoreY,
                                            float* __restrict__ out) {
  int g = threadIdx.x >> 5;
  int j = threadIdx.x & 31;
  int b = blockIdx.x * 2 + g;
  float tcol[NTAGS];
#pragma unroll
  for (int i = 0; i < NTAGS; i++) tcol[i] = trans[i * NTAGS + j];
  float la = (j == TAG_START) ? 0.f : NEGV;
  __shared__ float lash[2][NTAGS];
  for (int s = 0; s < SS; s++) {
    lash[g][j] = la;
    __syncthreads();
    float emv = em[((size_t)b * SS + s) * NTAGS + j];
    float m = -3.0e38f;
#pragma unroll
    for (int i = 0; i < NTAGS; i++) m = fmaxf(m, lash[g][i] + tcol[i]);
    float sum = 0.f;
#pragma unroll
    for (int i = 0; i < NTAGS; i++) sum += __expf(lash[g][i] + tcol[i] - m);
    float la2 = m + __logf(sum) + emv;
    float mk = (float)mask[b * SS + s];
    la = la2 * mk + la * (1.f - mk);
    __syncthreads();
  }
  la += trans[j * NTAGS + TAG_END];
  lash[g][j] = la;
  __syncthreads();
  float m = -3.0e38f;
#pragma unroll
  for (int i = 0; i < NTAGS; i++) m = fmaxf(m, lash[g][i]);
  float sum = 0.f;
#pragma unroll
  for (int i = 0; i < NTAGS; i++) sum += __expf(lash[g][i] - m);
  float total = m + __logf(sum);
  if (j == 0) atomicAdd(out, (total - scoreY[b]) * (1.0f / BB));
}

extern "C" void kernel_launch(void* const* d_in, const int* in_sizes, int n_in,
                              void* d_out, int out_size, void* d_ws, size_t ws_size,
                              hipStream_t stream) {
  const float* word_emb = (const float*)d_in[0];
  const float* char_emb = (const float*)d_in[1];
  const float* conv_w   = (const float*)d_in[2];
  const float* conv_b   = (const float*)d_in[3];
  const float* wih_f    = (const float*)d_in[4];
  const float* whh_f    = (const float*)d_in[5];
  const float* bih_f    = (const float*)d_in[6];
  const float* bhh_f    = (const float*)d_in[7];
  const float* wih_b    = (const float*)d_in[8];
  const float* whh_b    = (const float*)d_in[9];
  const float* bih_b    = (const float*)d_in[10];
  const float* bhh_b    = (const float*)d_in[11];
  const float* proj_w   = (const float*)d_in[12];
  const float* proj_b   = (const float*)d_in[13];
  const float* trans    = (const float*)d_in[14];
  const int* word_x     = (const int*)d_in[15];
  const int* char_x     = (const int*)d_in[16];
  const int* y          = (const int*)d_in[17];
  const int* mask       = (const int*)d_in[18];
  float* out = (float*)d_out;

  _Float16* x16 = (_Float16*)d_ws;                       // 32768*160 halves (10.49 MB)
  _Float16* w16 = x16 + (size_t)BB * SS * KPAD;          // 832*160 halves (266 KB)
  float* preF   = (float*)(w16 + (size_t)NROWS * KPAD);  // 32768*400 f32
  float* preB   = preF + (size_t)BB * SS * GDIM;
  float* hbuf   = preB + (size_t)BB * SS * GDIM;         // 32768*200
  float* em     = hbuf + (size_t)BB * SS * 2 * HDIM;     // 32768*32
  float* scoreY = em + (size_t)BB * SS * NTAGS;          // 128

  hipMemsetAsync(d_out, 0, sizeof(float), stream);
  k_word<<<(BB * SS * KPAD + 255) / 256, 256, 0, stream>>>(word_emb, word_x, x16);
  k_charconv<<<BB * SS / CTOK, 256, 0, stream>>>(char_emb, conv_w, conv_b, char_x, x16);
  k_wcvt<<<(NROWS * KPAD + 255) / 256, 256, 0, stream>>>(wih_f, wih_b, w16);
  k_pregemm<<<dim3(BB * SS / 64, 13), 256, 0, stream>>>(x16, w16, bih_f, bhh_f,
                                                        bih_b, bhh_b, preF, preB);
  k_lstm<<<256, 512, 0, stream>>>(preF, preB, whh_f, whh_b, hbuf);
  k_proj<<<(BB * SS * NTAGS + 255) / 256, 256, 0, stream>>>(hbuf, proj_w, proj_b, em);
  k_score<<<BB, 64, 0, stream>>>(em, trans, y, mask, scoreY);
  k_crf<<<BB / 2, 64, 0, stream>>>(em, trans, mask, scoreY, out);
}

// Round 12
// 649.825 us; speedup vs baseline: 1.2476x; 1.0298x over previous
//
#include <hip/hip_runtime.h>
#include <hip/hip_fp16.h>
#include <cstdint>
#include <cstddef>

#define BB 128
#define SS 256
#define LL 10
#define NTAGS 32
#define TAG_START 30
#define TAG_END 31
#define WDIM 100
#define CDIM 30
#define NFILT 30
#define HDIM 100
#define KIN 130      // LSTM_IN = WDIM + FILT
#define KPAD 160     // padded K for f16 GEMM operands
#define GDIM 400     // 4*H
#define NROWS 832    // 13*64 padded W rows
#define NEGV -10000.0f
#define CTOK 8       // tokens per charconv block

typedef _Float16 h2 __attribute__((ext_vector_type(2)));
typedef _Float16 f16x8 __attribute__((ext_vector_type(8)));
typedef float f32x4 __attribute__((ext_vector_type(4)));

__device__ __forceinline__ float sigm(float x) { return 1.0f / (1.0f + __expf(-x)); }
__device__ __forceinline__ float tanh_fast(float x) { return 2.0f / (1.0f + __expf(-2.0f * x)) - 1.0f; }

// ---------------- K1a: word embedding gather -> x16[:, 0:100], zero pad [130:160) ----------------
__global__ void k_word(const float* __restrict__ wemb, const int* __restrict__ wx,
                       _Float16* __restrict__ x16) {
  int idx = blockIdx.x * blockDim.x + threadIdx.x;
  if (idx >= BB * SS * KPAD) return;
  int token = idx / KPAD;
  int d = idx - token * KPAD;
  if (d < WDIM) {
    x16[idx] = (_Float16)wemb[(size_t)wx[token] * WDIM + d];
  } else if (d >= KIN) {
    x16[idx] = (_Float16)0.f;
  }
}

// ---------------- K1b: char conv + max-pool -> x16[:, 100:130] ----------------
__global__ __launch_bounds__(256) void k_charconv(const float* __restrict__ cemb,
                                                  const float* __restrict__ convw,
                                                  const float* __restrict__ convb,
                                                  const int* __restrict__ cx,
                                                  _Float16* __restrict__ x16) {
  int blk = blockIdx.x;
  int tid = threadIdx.x;
  int tok8 = tid >> 5;
  int f = tid & 31;
  int token0 = blk * CTOK;
  __shared__ float e[CTOK][LL * CDIM];
  __shared__ int ci[CTOK][LL];
  if (tid < CTOK * LL) {
    int t = tid / LL, l = tid - t * LL;
    ci[t][l] = cx[(token0 + t) * LL + l];
  }
  __syncthreads();
  for (int i = tid; i < CTOK * LL * CDIM; i += 256) {
    int t = i / (LL * CDIM);
    int r = i - t * (LL * CDIM);
    int l = r / CDIM, c = r - l * CDIM;
    e[t][l * CDIM + c] = cemb[ci[t][l] * CDIM + c];
  }
  __syncthreads();
  if (f < NFILT) {
    float d0[LL], d1[LL], d2[LL];
#pragma unroll
    for (int l = 0; l < LL; l++) { d0[l] = 0.f; d1[l] = 0.f; d2[l] = 0.f; }
    const float* et = &e[tok8][0];
    for (int c = 0; c < CDIM; c++) {
      float w0 = convw[(f * 3 + 0) * CDIM + c];
      float w1 = convw[(f * 3 + 1) * CDIM + c];
      float w2 = convw[(f * 3 + 2) * CDIM + c];
#pragma unroll
      for (int l = 0; l < LL; l++) {
        float ev = et[l * CDIM + c];
        d0[l] += ev * w0; d1[l] += ev * w1; d2[l] += ev * w2;
      }
    }
    float bias = convb[f];
    float m = -3.0e38f;
#pragma unroll
    for (int h = 0; h < LL + 2; h++) {
      float acc = bias;
      int j0 = h - 2, j1 = h - 1, j2 = h;
      if (j0 >= 0 && j0 < LL) acc += d0[j0];
      if (j1 >= 0 && j1 < LL) acc += d1[j1];
      if (j2 >= 0 && j2 < LL) acc += d2[j2];
      m = fmaxf(m, acc);
    }
    x16[(size_t)(token0 + tok8) * KPAD + WDIM + f] = (_Float16)m;
  }
}

// ---------------- K1c: W (wih_f | wih_b) -> f16 [832][160], padded zeros ----------------
__global__ void k_wcvt(const float* __restrict__ wihF, const float* __restrict__ wihB,
                       _Float16* __restrict__ w16) {
  int idx = blockIdx.x * blockDim.x + threadIdx.x;
  if (idx >= NROWS * KPAD) return;
  int n = idx / KPAD;
  int k = idx - n * KPAD;
  float v = 0.f;
  if (k < KIN && n < 2 * GDIM) {
    v = (n < GDIM) ? wihF[(size_t)n * KIN + k] : wihB[(size_t)(n - GDIM) * KIN + k];
  }
  w16[idx] = (_Float16)v;
}

// ---------------- K2: pre = x @ wih^T + (bih+bhh), MFMA f16, f16 output ----------------
__global__ __launch_bounds__(256) void k_pregemm(
    const _Float16* __restrict__ x16, const _Float16* __restrict__ w16,
    const float* __restrict__ bihF, const float* __restrict__ bhhF,
    const float* __restrict__ bihB, const float* __restrict__ bhhB,
    _Float16* __restrict__ preF, _Float16* __restrict__ preB) {
  __shared__ __align__(16) _Float16 Asl[64 * 40];
  __shared__ __align__(16) _Float16 Bsl[64 * 40];
  int m0 = blockIdx.x * 64;
  int n0 = blockIdx.y * 64;
  int tid = threadIdx.x;
  int lane = tid & 63, w = tid >> 6;
  int quad = lane >> 4, l15 = lane & 15;

  f32x4 acc[4];
#pragma unroll
  for (int i = 0; i < 4; i++) acc[i] = (f32x4){0.f, 0.f, 0.f, 0.f};

  int r = tid >> 2;            // staging row 0..63
  int kk = (tid & 3) * 8;      // k offset within chunk
  const _Float16* xs = x16 + (size_t)(m0 + r) * KPAD + kk;
  const _Float16* wsrc = w16 + (size_t)(n0 + r) * KPAD + kk;

  for (int kc = 0; kc < 5; kc++) {
    if (kc) __syncthreads();
    *(f16x8*)&Asl[r * 40 + kk] = *(const f16x8*)(xs + kc * 32);
    *(f16x8*)&Bsl[r * 40 + kk] = *(const f16x8*)(wsrc + kc * 32);
    __syncthreads();

    f16x8 bfrag = *(const f16x8*)&Bsl[(w * 16 + l15) * 40 + quad * 8];
#pragma unroll
    for (int mt = 0; mt < 4; mt++) {
      f16x8 afrag = *(const f16x8*)&Asl[(mt * 16 + l15) * 40 + quad * 8];
      acc[mt] = __builtin_amdgcn_mfma_f32_16x16x32_f16(afrag, bfrag, acc[mt], 0, 0, 0);
    }
  }

  int ng = n0 + w * 16 + l15;  // this lane's output column (fixed)
  if (ng < 2 * GDIM) {
    int dir = ng >= GDIM;
    int jb = dir ? ng - GDIM : ng;
    _Float16* dst = dir ? preB : preF;
    float bias = (dir ? bihB : bihF)[jb] + (dir ? bhhB : bhhF)[jb];
#pragma unroll
    for (int mt = 0; mt < 4; mt++) {
#pragma unroll
      for (int i = 0; i < 4; i++) {
        int m = m0 + mt * 16 + quad * 4 + i;
        dst[(size_t)m * GDIM + jb] = (_Float16)(acc[mt][i] + bias);
      }
    }
  }
}

// ---------------- K3: recurrent LSTM scan, K-split-2, 832 threads ----------------
// Spill-proof by construction: per-thread weights = 28 packed-f16 VGPRs
// (7 chunks x 8 halves). Group A (tid<416, rows 0..399) covers k-chunks 0..6,
// group B (tid>=416) chunks 7..13; weights for k>=100 and h LDS halves
// 100..111 are zero, so both groups run a uniform unrolled 7-chunk loop.
// Partials meet in gpart[2][400]; gate threads (tid<100) sum pairs.
// Plain __syncthreads; 2-deep f16 pre prefetch (group A only). K-split logic
// proven in R5; f16 weights/h proven in R8 (absmax 0.0).
__global__ __launch_bounds__(832) void k_lstm(
    const _Float16* __restrict__ preF, const _Float16* __restrict__ preB,
    const float* __restrict__ whhF, const float* __restrict__ whhB,
    _Float16* __restrict__ hbuf) {
  int blk = blockIdx.x;
  int dir = blk >> 7;   // 0 fwd, 1 bwd
  int b = blk & 127;
  const _Float16* pre = dir ? preB : preF;
  const float* whh = dir ? whhB : whhF;
  int tid = threadIdx.x;
  int grp = (tid >= 416) ? 1 : 0;
  int r = grp ? (tid - 416) : tid;      // gate row
  bool act = (r < GDIM);
  int rc = act ? r : 0;
  int c0 = grp * 7;                      // first h/weight chunk

  h2 wp[28];   // 7 chunks x 4 h2 = 56 halves = 28 VGPRs
  {
    const float* wr = whh + (size_t)rc * HDIM;
#pragma unroll
    for (int cc = 0; cc < 7; cc++) {
#pragma unroll
      for (int q = 0; q < 4; q++) {
        int k0 = (c0 + cc) * 8 + q * 2;
        h2 hw;
        hw.x = (_Float16)(k0 < HDIM ? wr[k0] : 0.f);
        hw.y = (_Float16)(k0 + 1 < HDIM ? wr[k0 + 1] : 0.f);
        wp[cc * 4 + q] = hw;
      }
    }
  }

  __shared__ __align__(16) _Float16 hsh16[2][112];
  __shared__ float gpart[2][GDIM];
  if (tid < 112) { hsh16[0][tid] = (_Float16)0.f; hsh16[1][tid] = (_Float16)0.f; }
  float c = 0.f;

  const _Float16* pbase = pre + ((size_t)b * SS + (dir ? (SS - 1) : 0)) * GDIM + rc;
  const intptr_t pstep = dir ? -(intptr_t)GDIM : (intptr_t)GDIM;

  float p0 = 0.f, p1 = 0.f;
  if (act && grp == 0) { p0 = (float)pbase[0]; p1 = (float)pbase[pstep]; }
  __syncthreads();

  int cur = 0;
  for (int step = 0; step < SS; step++) {
    float p2 = 0.f;
    if (act && grp == 0) {
      int tn = (step + 2 < SS) ? (step + 2) : (SS - 1);
      p2 = (float)pbase[(intptr_t)tn * pstep];
    }

    if (act) {
      const uint4* h4 = (const uint4*)&hsh16[cur][0];
      float acc = grp ? 0.f : p0;
#pragma unroll
      for (int cc = 0; cc < 7; cc++) {
        uint4 hv = h4[c0 + cc];
        h2 ha = __builtin_bit_cast(h2, hv.x);
        h2 hb = __builtin_bit_cast(h2, hv.y);
        h2 hc = __builtin_bit_cast(h2, hv.z);
        h2 hd = __builtin_bit_cast(h2, hv.w);
        h2 wa = wp[cc * 4 + 0], wb = wp[cc * 4 + 1];
        h2 wc = wp[cc * 4 + 2], wd = wp[cc * 4 + 3];
        acc = fmaf((float)ha.x, (float)wa.x, acc);
        acc = fmaf((float)ha.y, (float)wa.y, acc);
        acc = fmaf((float)hb.x, (float)wb.x, acc);
        acc = fmaf((float)hb.y, (float)wb.y, acc);
        acc = fmaf((float)hc.x, (float)wc.x, acc);
        acc = fmaf((float)hc.y, (float)wc.y, acc);
        acc = fmaf((float)hd.x, (float)wd.x, acc);
        acc = fmaf((float)hd.y, (float)wd.y, acc);
      }
      gpart[grp][r] = acc;
    }
    __syncthreads();
    if (tid < HDIM) {
      int j = tid;
      float gi = gpart[0][j] + gpart[1][j];
      float gf = gpart[0][j + HDIM] + gpart[1][j + HDIM];
      float gg = gpart[0][j + 2 * HDIM] + gpart[1][j + 2 * HDIM];
      float go = gpart[0][j + 3 * HDIM] + gpart[1][j + 3 * HDIM];
      float ig = sigm(gi), fg = sigm(gf), g2 = tanh_fast(gg), og = sigm(go);
      c = fg * c + ig * g2;
      float h = og * tanh_fast(c);
      hsh16[cur ^ 1][j] = (_Float16)h;
      int t = dir ? (SS - 1 - step) : step;
      hbuf[((size_t)b * SS + t) * (2 * HDIM) + dir * HDIM + j] = (_Float16)h;
    }
    __syncthreads();
    p0 = p1; p1 = p2;
    cur ^= 1;
  }
}

// ---------------- K4: emission = [h_f,h_b] @ proj_w^T + proj_b ----------------
__global__ void k_proj(const _Float16* __restrict__ hbuf, const float* __restrict__ pw,
                       const float* __restrict__ pb, float* __restrict__ em) {
  int idx = blockIdx.x * blockDim.x + threadIdx.x;  // token*32 + tag
  if (idx >= BB * SS * NTAGS) return;
  int token = idx >> 5, tag = idx & 31;
  const uint4* h4 = (const uint4*)(hbuf + (size_t)token * 2 * HDIM);
  const float* wrow = pw + (size_t)tag * 2 * HDIM;
  float acc = pb[tag];
#pragma unroll
  for (int k = 0; k < 25; k++) {
    uint4 hv = h4[k];
    h2 a = __builtin_bit_cast(h2, hv.x);
    h2 bq = __builtin_bit_cast(h2, hv.y);
    h2 cq = __builtin_bit_cast(h2, hv.z);
    h2 d = __builtin_bit_cast(h2, hv.w);
    const float4* w4 = (const float4*)(wrow + k * 8);
    float4 w0 = w4[0], w1 = w4[1];
    acc += (float)a.x * w0.x + (float)a.y * w0.y + (float)bq.x * w0.z + (float)bq.y * w0.w
         + (float)cq.x * w1.x + (float)cq.y * w1.y + (float)d.x * w1.z + (float)d.y * w1.w;
  }
  em[idx] = acc;
}

// ---------------- K5: gold path score per batch ----------------
__global__ __launch_bounds__(64) void k_score(const float* __restrict__ em,
                                              const float* __restrict__ trans,
                                              const int* __restrict__ y,
                                              const int* __restrict__ mask,
                                              float* __restrict__ scoreY) {
  int b = blockIdx.x, l = threadIdx.x;
  float acc = 0.f;
  for (int s = l; s < SS; s += 64) {
    int curt = y[b * SS + s];
    int prevt = (s == 0) ? TAG_START : y[b * SS + s - 1];
    float mk = (float)mask[b * SS + s];
    acc += (em[((size_t)b * SS + s) * NTAGS + curt] + trans[prevt * NTAGS + curt]) * mk;
  }
#pragma unroll
  for (int off = 32; off > 0; off >>= 1) acc += __shfl_down(acc, off);
  if (l == 0) scoreY[b] = acc + trans[y[b * SS + SS - 1] * NTAGS + TAG_END];
}

// ---------------- K6: CRF forward (partition function) + loss ----------------
__global__ __launch_bounds__(64) void k_crf(const float* __restrict__ em,
                                            const float* __restrict__ trans,
                                            const int* __restrict__ mask,
                                            const float* __restrict__ scoreY,
                                            float* __restrict__ out) {
  int g = threadIdx.x >> 5;
  int j = threadIdx.x & 31;
  int b = blockIdx.x * 2 + g;
  float tcol[NTAGS];
#pragma unroll
  for (int i = 0; i < NTAGS; i++) tcol[i] = trans[i * NTAGS + j];
  float la = (j == TAG_START) ? 0.f : NEGV;
  __shared__ float lash[2][NTAGS];
  for (int s = 0; s < SS; s++) {
    lash[g][j] = la;
    __syncthreads();
    float emv = em[((size_t)b * SS + s) * NTAGS + j];
    float m = -3.0e38f;
#pragma unroll
    for (int i = 0; i < NTAGS; i++) m = fmaxf(m, lash[g][i] + tcol[i]);
    float sum = 0.f;
#pragma unroll
    for (int i = 0; i < NTAGS; i++) sum += __expf(lash[g][i] + tcol[i] - m);
    float la2 = m + __logf(sum) + emv;
    float mk = (float)mask[b * SS + s];
    la = la2 * mk + la * (1.f - mk);
    __syncthreads();
  }
  la += trans[j * NTAGS + TAG_END];
  lash[g][j] = la;
  __syncthreads();
  float m = -3.0e38f;
#pragma unroll
  for (int i = 0; i < NTAGS; i++) m = fmaxf(m, lash[g][i]);
  float sum = 0.f;
#pragma unroll
  for (int i = 0; i < NTAGS; i++) sum += __expf(lash[g][i] - m);
  float total = m + __logf(sum);
  if (j == 0) atomicAdd(out, (total - scoreY[b]) * (1.0f / BB));
}

extern "C" void kernel_launch(void* const* d_in, const int* in_sizes, int n_in,
                              void* d_out, int out_size, void* d_ws, size_t ws_size,
                              hipStream_t stream) {
  const float* word_emb = (const float*)d_in[0];
  const float* char_emb = (const float*)d_in[1];
  const float* conv_w   = (const float*)d_in[2];
  const float* conv_b   = (const float*)d_in[3];
  const float* wih_f    = (const float*)d_in[4];
  const float* whh_f    = (const float*)d_in[5];
  const float* bih_f    = (const float*)d_in[6];
  const float* bhh_f    = (const float*)d_in[7];
  const float* wih_b    = (const float*)d_in[8];
  const float* whh_b    = (const float*)d_in[9];
  const float* bih_b    = (const float*)d_in[10];
  const float* bhh_b    = (const float*)d_in[11];
  const float* proj_w   = (const float*)d_in[12];
  const float* proj_b   = (const float*)d_in[13];
  const float* trans    = (const float*)d_in[14];
  const int* word_x     = (const int*)d_in[15];
  const int* char_x     = (const int*)d_in[16];
  const int* y          = (const int*)d_in[17];
  const int* mask       = (const int*)d_in[18];
  float* out = (float*)d_out;

  _Float16* x16   = (_Float16*)d_ws;                     // 32768*160 halves
  _Float16* w16   = x16 + (size_t)BB * SS * KPAD;        // 832*160 halves
  _Float16* preF  = w16 + (size_t)NROWS * KPAD;          // 32768*400 halves
  _Float16* preB  = preF + (size_t)BB * SS * GDIM;       // 32768*400 halves
  _Float16* hbuf  = preB + (size_t)BB * SS * GDIM;       // 32768*200 halves
  float* em       = (float*)(hbuf + (size_t)BB * SS * 2 * HDIM);  // 32768*32 f32
  float* scoreY   = em + (size_t)BB * SS * NTAGS;        // 128

  hipMemsetAsync(d_out, 0, sizeof(float), stream);
  k_word<<<(BB * SS * KPAD + 255) / 256, 256, 0, stream>>>(word_emb, word_x, x16);
  k_charconv<<<BB * SS / CTOK, 256, 0, stream>>>(char_emb, conv_w, conv_b, char_x, x16);
  k_wcvt<<<(NROWS * KPAD + 255) / 256, 256, 0, stream>>>(wih_f, wih_b, w16);
  k_pregemm<<<dim3(BB * SS / 64, 13), 256, 0, stream>>>(x16, w16, bih_f, bhh_f,
                                                        bih_b, bhh_b, preF, preB);
  k_lstm<<<256, 832, 0, stream>>>(preF, preB, whh_f, whh_b, hbuf);
  k_proj<<<(BB * SS * NTAGS + 255) / 256, 256, 0, stream>>>(hbuf, proj_w, proj_b, em);
  k_score<<<BB, 64, 0, stream>>>(em, trans, y, mask, scoreY);
  k_crf<<<BB / 2, 64, 0, stream>>>(em, trans, mask, scoreY, out);
}

// Round 13
// 616.674 us; speedup vs baseline: 1.3147x; 1.0538x over previous
//
#include <hip/hip_runtime.h>
#include <hip/hip_fp16.h>
#include <cstdint>
#include <cstddef>

#define BB 128
#define SS 256
#define LL 10
#define NTAGS 32
#define TAG_START 30
#define TAG_END 31
#define WDIM 100
#define CDIM 30
#define NFILT 30
#define HDIM 100
#define KIN 130      // LSTM_IN = WDIM + FILT
#define KPAD 160     // padded K for f16 GEMM operands
#define GDIM 400     // 4*H
#define NROWS 832    // 13*64 padded W rows
#define NEGV -10000.0f
#define CTOK 8       // tokens per charconv block

typedef _Float16 h2 __attribute__((ext_vector_type(2)));
typedef _Float16 f16x8 __attribute__((ext_vector_type(8)));
typedef float f32x4 __attribute__((ext_vector_type(4)));

__device__ __forceinline__ float sigm(float x) { return 1.0f / (1.0f + __expf(-x)); }
__device__ __forceinline__ float tanh_fast(float x) { return 2.0f / (1.0f + __expf(-2.0f * x)) - 1.0f; }

// ---------------- K1a: word embedding gather -> x16[:, 0:100], zero pad [130:160) ----------------
__global__ void k_word(const float* __restrict__ wemb, const int* __restrict__ wx,
                       _Float16* __restrict__ x16) {
  int idx = blockIdx.x * blockDim.x + threadIdx.x;
  if (idx >= BB * SS * KPAD) return;
  int token = idx / KPAD;
  int d = idx - token * KPAD;
  if (d < WDIM) {
    x16[idx] = (_Float16)wemb[(size_t)wx[token] * WDIM + d];
  } else if (d >= KIN) {
    x16[idx] = (_Float16)0.f;
  }
}

// ---------------- K1b: char conv + max-pool -> x16[:, 100:130] ----------------
__global__ __launch_bounds__(256) void k_charconv(const float* __restrict__ cemb,
                                                  const float* __restrict__ convw,
                                                  const float* __restrict__ convb,
                                                  const int* __restrict__ cx,
                                                  _Float16* __restrict__ x16) {
  int blk = blockIdx.x;
  int tid = threadIdx.x;
  int tok8 = tid >> 5;
  int f = tid & 31;
  int token0 = blk * CTOK;
  __shared__ float e[CTOK][LL * CDIM];
  __shared__ int ci[CTOK][LL];
  if (tid < CTOK * LL) {
    int t = tid / LL, l = tid - t * LL;
    ci[t][l] = cx[(token0 + t) * LL + l];
  }
  __syncthreads();
  for (int i = tid; i < CTOK * LL * CDIM; i += 256) {
    int t = i / (LL * CDIM);
    int r = i - t * (LL * CDIM);
    int l = r / CDIM, c = r - l * CDIM;
    e[t][l * CDIM + c] = cemb[ci[t][l] * CDIM + c];
  }
  __syncthreads();
  if (f < NFILT) {
    float d0[LL], d1[LL], d2[LL];
#pragma unroll
    for (int l = 0; l < LL; l++) { d0[l] = 0.f; d1[l] = 0.f; d2[l] = 0.f; }
    const float* et = &e[tok8][0];
    for (int c = 0; c < CDIM; c++) {
      float w0 = convw[(f * 3 + 0) * CDIM + c];
      float w1 = convw[(f * 3 + 1) * CDIM + c];
      float w2 = convw[(f * 3 + 2) * CDIM + c];
#pragma unroll
      for (int l = 0; l < LL; l++) {
        float ev = et[l * CDIM + c];
        d0[l] += ev * w0; d1[l] += ev * w1; d2[l] += ev * w2;
      }
    }
    float bias = convb[f];
    float m = -3.0e38f;
#pragma unroll
    for (int h = 0; h < LL + 2; h++) {
      float acc = bias;
      int j0 = h - 2, j1 = h - 1, j2 = h;
      if (j0 >= 0 && j0 < LL) acc += d0[j0];
      if (j1 >= 0 && j1 < LL) acc += d1[j1];
      if (j2 >= 0 && j2 < LL) acc += d2[j2];
      m = fmaxf(m, acc);
    }
    x16[(size_t)(token0 + tok8) * KPAD + WDIM + f] = (_Float16)m;
  }
}

// ---------------- K1c: W (wih_f | wih_b) -> f16 [832][160], padded zeros ----------------
__global__ void k_wcvt(const float* __restrict__ wihF, const float* __restrict__ wihB,
                       _Float16* __restrict__ w16) {
  int idx = blockIdx.x * blockDim.x + threadIdx.x;
  if (idx >= NROWS * KPAD) return;
  int n = idx / KPAD;
  int k = idx - n * KPAD;
  float v = 0.f;
  if (k < KIN && n < 2 * GDIM) {
    v = (n < GDIM) ? wihF[(size_t)n * KIN + k] : wihB[(size_t)(n - GDIM) * KIN + k];
  }
  w16[idx] = (_Float16)v;
}

// ---------------- K2: pre = x @ wih^T + (bih+bhh), MFMA f16, f16 output ----------------
__global__ __launch_bounds__(256) void k_pregemm(
    const _Float16* __restrict__ x16, const _Float16* __restrict__ w16,
    const float* __restrict__ bihF, const float* __restrict__ bhhF,
    const float* __restrict__ bihB, const float* __restrict__ bhhB,
    _Float16* __restrict__ preF, _Float16* __restrict__ preB) {
  __shared__ __align__(16) _Float16 Asl[64 * 40];
  __shared__ __align__(16) _Float16 Bsl[64 * 40];
  int m0 = blockIdx.x * 64;
  int n0 = blockIdx.y * 64;
  int tid = threadIdx.x;
  int lane = tid & 63, w = tid >> 6;
  int quad = lane >> 4, l15 = lane & 15;

  f32x4 acc[4];
#pragma unroll
  for (int i = 0; i < 4; i++) acc[i] = (f32x4){0.f, 0.f, 0.f, 0.f};

  int r = tid >> 2;            // staging row 0..63
  int kk = (tid & 3) * 8;      // k offset within chunk
  const _Float16* xs = x16 + (size_t)(m0 + r) * KPAD + kk;
  const _Float16* wsrc = w16 + (size_t)(n0 + r) * KPAD + kk;

  for (int kc = 0; kc < 5; kc++) {
    if (kc) __syncthreads();
    *(f16x8*)&Asl[r * 40 + kk] = *(const f16x8*)(xs + kc * 32);
    *(f16x8*)&Bsl[r * 40 + kk] = *(const f16x8*)(wsrc + kc * 32);
    __syncthreads();

    f16x8 bfrag = *(const f16x8*)&Bsl[(w * 16 + l15) * 40 + quad * 8];
#pragma unroll
    for (int mt = 0; mt < 4; mt++) {
      f16x8 afrag = *(const f16x8*)&Asl[(mt * 16 + l15) * 40 + quad * 8];
      acc[mt] = __builtin_amdgcn_mfma_f32_16x16x32_f16(afrag, bfrag, acc[mt], 0, 0, 0);
    }
  }

  int ng = n0 + w * 16 + l15;  // this lane's output column (fixed)
  if (ng < 2 * GDIM) {
    int dir = ng >= GDIM;
    int jb = dir ? ng - GDIM : ng;
    _Float16* dst = dir ? preB : preF;
    float bias = (dir ? bihB : bihF)[jb] + (dir ? bhhB : bhhF)[jb];
#pragma unroll
    for (int mt = 0; mt < 4; mt++) {
#pragma unroll
      for (int i = 0; i < 4; i++) {
        int m = m0 + mt * 16 + quad * 4 + i;
        dst[(size_t)m * GDIM + jb] = (_Float16)(acc[mt][i] + bias);
      }
    }
  }
}

// ---------------- K3: recurrent LSTM scan, K-split-2, 832 threads ----------------
// R12 structure (proven, VGPR 48, no spill) with ONE delta: the dot phase uses
// __hfma2 (v_pk_fma_f16, 2 MACs/instr) into 4 independent __half2 accumulators
// instead of 8 cast+fma per chunk -> VALU instr/thread/step ~160 -> ~60.
// Accumulators are per-step (reset each iteration), so f16 accumulation error
// is within-step only (~1e-3 on O(1) gate pre-activations). Final combine f32.
__global__ __launch_bounds__(832) void k_lstm(
    const _Float16* __restrict__ preF, const _Float16* __restrict__ preB,
    const float* __restrict__ whhF, const float* __restrict__ whhB,
    _Float16* __restrict__ hbuf) {
  int blk = blockIdx.x;
  int dir = blk >> 7;   // 0 fwd, 1 bwd
  int b = blk & 127;
  const _Float16* pre = dir ? preB : preF;
  const float* whh = dir ? whhB : whhF;
  int tid = threadIdx.x;
  int grp = (tid >= 416) ? 1 : 0;
  int r = grp ? (tid - 416) : tid;      // gate row
  bool act = (r < GDIM);
  int rc = act ? r : 0;
  int c0 = grp * 7;                      // first h/weight chunk

  __half2 wp[28];   // 7 chunks x 4 half2 = 56 halves = 28 VGPRs
  {
    const float* wr = whh + (size_t)rc * HDIM;
#pragma unroll
    for (int cc = 0; cc < 7; cc++) {
#pragma unroll
      for (int q = 0; q < 4; q++) {
        int k0 = (c0 + cc) * 8 + q * 2;
        float w0 = (k0 < HDIM) ? wr[k0] : 0.f;
        float w1 = (k0 + 1 < HDIM) ? wr[k0 + 1] : 0.f;
        wp[cc * 4 + q] = __floats2half2_rn(w0, w1);
      }
    }
  }

  __shared__ __align__(16) _Float16 hsh16[2][112];
  __shared__ float gpart[2][GDIM];
  if (tid < 112) { hsh16[0][tid] = (_Float16)0.f; hsh16[1][tid] = (_Float16)0.f; }
  float c = 0.f;

  const _Float16* pbase = pre + ((size_t)b * SS + (dir ? (SS - 1) : 0)) * GDIM + rc;
  const intptr_t pstep = dir ? -(intptr_t)GDIM : (intptr_t)GDIM;

  float p0 = 0.f, p1 = 0.f;
  if (act && grp == 0) { p0 = (float)pbase[0]; p1 = (float)pbase[pstep]; }
  __syncthreads();

  int cur = 0;
  for (int step = 0; step < SS; step++) {
    float p2 = 0.f;
    if (act && grp == 0) {
      int tn = (step + 2 < SS) ? (step + 2) : (SS - 1);
      p2 = (float)pbase[(intptr_t)tn * pstep];
    }

    if (act) {
      const uint4* h4 = (const uint4*)&hsh16[cur][0];
      __half2 z = __floats2half2_rn(0.f, 0.f);
      __half2 a0 = z, a1 = z, a2 = z, a3 = z;
#pragma unroll
      for (int cc = 0; cc < 7; cc++) {
        uint4 hv = h4[c0 + cc];
        a0 = __hfma2(wp[cc * 4 + 0], __builtin_bit_cast(__half2, hv.x), a0);
        a1 = __hfma2(wp[cc * 4 + 1], __builtin_bit_cast(__half2, hv.y), a1);
        a2 = __hfma2(wp[cc * 4 + 2], __builtin_bit_cast(__half2, hv.z), a2);
        a3 = __hfma2(wp[cc * 4 + 3], __builtin_bit_cast(__half2, hv.w), a3);
      }
      float s0 = __low2float(a0) + __high2float(a0);
      float s1 = __low2float(a1) + __high2float(a1);
      float s2 = __low2float(a2) + __high2float(a2);
      float s3 = __low2float(a3) + __high2float(a3);
      float acc = (grp ? 0.f : p0) + ((s0 + s1) + (s2 + s3));
      gpart[grp][r] = acc;
    }
    __syncthreads();
    if (tid < HDIM) {
      int j = tid;
      float gi = gpart[0][j] + gpart[1][j];
      float gf = gpart[0][j + HDIM] + gpart[1][j + HDIM];
      float gg = gpart[0][j + 2 * HDIM] + gpart[1][j + 2 * HDIM];
      float go = gpart[0][j + 3 * HDIM] + gpart[1][j + 3 * HDIM];
      float ig = sigm(gi), fg = sigm(gf), g2 = tanh_fast(gg), og = sigm(go);
      c = fg * c + ig * g2;
      float h = og * tanh_fast(c);
      hsh16[cur ^ 1][j] = (_Float16)h;
      int t = dir ? (SS - 1 - step) : step;
      hbuf[((size_t)b * SS + t) * (2 * HDIM) + dir * HDIM + j] = (_Float16)h;
    }
    __syncthreads();
    p0 = p1; p1 = p2;
    cur ^= 1;
  }
}

// ---------------- K4: emission = [h_f,h_b] @ proj_w^T + proj_b ----------------
__global__ void k_proj(const _Float16* __restrict__ hbuf, const float* __restrict__ pw,
                       const float* __restrict__ pb, float* __restrict__ em) {
  int idx = blockIdx.x * blockDim.x + threadIdx.x;  // token*32 + tag
  if (idx >= BB * SS * NTAGS) return;
  int token = idx >> 5, tag = idx & 31;
  const uint4* h4 = (const uint4*)(hbuf + (size_t)token * 2 * HDIM);
  const float* wrow = pw + (size_t)tag * 2 * HDIM;
  float acc = pb[tag];
#pragma unroll
  for (int k = 0; k < 25; k++) {
    uint4 hv = h4[k];
    h2 a = __builtin_bit_cast(h2, hv.x);
    h2 bq = __builtin_bit_cast(h2, hv.y);
    h2 cq = __builtin_bit_cast(h2, hv.z);
    h2 d = __builtin_bit_cast(h2, hv.w);
    const float4* w4 = (const float4*)(wrow + k * 8);
    float4 w0 = w4[0], w1 = w4[1];
    acc += (float)a.x * w0.x + (float)a.y * w0.y + (float)bq.x * w0.z + (float)bq.y * w0.w
         + (float)cq.x * w1.x + (float)cq.y * w1.y + (float)d.x * w1.z + (float)d.y * w1.w;
  }
  em[idx] = acc;
}

// ---------------- K5: gold path score per batch ----------------
__global__ __launch_bounds__(64) void k_score(const float* __restrict__ em,
                                              const float* __restrict__ trans,
                                              const int* __restrict__ y,
                                              const int* __restrict__ mask,
                                              float* __restrict__ scoreY) {
  int b = blockIdx.x, l = threadIdx.x;
  float acc = 0.f;
  for (int s = l; s < SS; s += 64) {
    int curt = y[b * SS + s];
    int prevt = (s == 0) ? TAG_START : y[b * SS + s - 1];
    float mk = (float)mask[b * SS + s];
    acc += (em[((size_t)b * SS + s) * NTAGS + curt] + trans[prevt * NTAGS + curt]) * mk;
  }
#pragma unroll
  for (int off = 32; off > 0; off >>= 1) acc += __shfl_down(acc, off);
  if (l == 0) scoreY[b] = acc + trans[y[b * SS + SS - 1] * NTAGS + TAG_END];
}

// ---------------- K6: CRF forward (partition function) + loss ----------------
// Only 64 waves device-wide (parallelism bounded by B): the per-step em/mask
// load latency was fully exposed. 2-deep prefetch (em[s] is independent of
// the la recurrence) hides it, same pattern as k_lstm's pre prefetch.
__global__ __launch_bounds__(64) void k_crf(const float* __restrict__ em,
                                            const float* __restrict__ trans,
                                            const int* __restrict__ mask,
                                            const float* __restrict__ scoreY,
                                            float* __restrict__ out) {
  int g = threadIdx.x >> 5;
  int j = threadIdx.x & 31;
  int b = blockIdx.x * 2 + g;
  float tcol[NTAGS];
#pragma unroll
  for (int i = 0; i < NTAGS; i++) tcol[i] = trans[i * NTAGS + j];
  float la = (j == TAG_START) ? 0.f : NEGV;
  __shared__ float lash[2][NTAGS];

  const float* emb = em + (size_t)b * SS * NTAGS + j;
  const int* mkb = mask + b * SS;
  float e0 = emb[0], e1 = emb[NTAGS];
  int m0i = mkb[0], m1i = mkb[1];

  for (int s = 0; s < SS; s++) {
    int sn = (s + 2 < SS) ? (s + 2) : (SS - 1);
    float e2 = emb[(size_t)sn * NTAGS];
    int m2i = mkb[sn];

    lash[g][j] = la;
    __syncthreads();
    float m = -3.0e38f;
#pragma unroll
    for (int i = 0; i < NTAGS; i++) m = fmaxf(m, lash[g][i] + tcol[i]);
    float sum = 0.f;
#pragma unroll
    for (int i = 0; i < NTAGS; i++) sum += __expf(lash[g][i] + tcol[i] - m);
    float la2 = m + __logf(sum) + e0;
    float mk = (float)m0i;
    la = la2 * mk + la * (1.f - mk);
    __syncthreads();
    e0 = e1; e1 = e2; m0i = m1i; m1i = m2i;
  }
  la += trans[j * NTAGS + TAG_END];
  lash[g][j] = la;
  __syncthreads();
  float m = -3.0e38f;
#pragma unroll
  for (int i = 0; i < NTAGS; i++) m = fmaxf(m, lash[g][i]);
  float sum = 0.f;
#pragma unroll
  for (int i = 0; i < NTAGS; i++) sum += __expf(lash[g][i] - m);
  float total = m + __logf(sum);
  if (j == 0) atomicAdd(out, (total - scoreY[b]) * (1.0f / BB));
}

extern "C" void kernel_launch(void* const* d_in, const int* in_sizes, int n_in,
                              void* d_out, int out_size, void* d_ws, size_t ws_size,
                              hipStream_t stream) {
  const float* word_emb = (const float*)d_in[0];
  const float* char_emb = (const float*)d_in[1];
  const float* conv_w   = (const float*)d_in[2];
  const float* conv_b   = (const float*)d_in[3];
  const float* wih_f    = (const float*)d_in[4];
  const float* whh_f    = (const float*)d_in[5];
  const float* bih_f    = (const float*)d_in[6];
  const float* bhh_f    = (const float*)d_in[7];
  const float* wih_b    = (const float*)d_in[8];
  const float* whh_b    = (const float*)d_in[9];
  const float* bih_b    = (const float*)d_in[10];
  const float* bhh_b    = (const float*)d_in[11];
  const float* proj_w   = (const float*)d_in[12];
  const float* proj_b   = (const float*)d_in[13];
  const float* trans    = (const float*)d_in[14];
  const int* word_x     = (const int*)d_in[15];
  const int* char_x     = (const int*)d_in[16];
  const int* y          = (const int*)d_in[17];
  const int* mask       = (const int*)d_in[18];
  float* out = (float*)d_out;

  _Float16* x16   = (_Float16*)d_ws;                     // 32768*160 halves
  _Float16* w16   = x16 + (size_t)BB * SS * KPAD;        // 832*160 halves
  _Float16* preF  = w16 + (size_t)NROWS * KPAD;          // 32768*400 halves
  _Float16* preB  = preF + (size_t)BB * SS * GDIM;       // 32768*400 halves
  _Float16* hbuf  = preB + (size_t)BB * SS * GDIM;       // 32768*200 halves
  float* em       = (float*)(hbuf + (size_t)BB * SS * 2 * HDIM);  // 32768*32 f32
  float* scoreY   = em + (size_t)BB * SS * NTAGS;        // 128

  hipMemsetAsync(d_out, 0, sizeof(float), stream);
  k_word<<<(BB * SS * KPAD + 255) / 256, 256, 0, stream>>>(word_emb, word_x, x16);
  k_charconv<<<BB * SS / CTOK, 256, 0, stream>>>(char_emb, conv_w, conv_b, char_x, x16);
  k_wcvt<<<(NROWS * KPAD + 255) / 256, 256, 0, stream>>>(wih_f, wih_b, w16);
  k_pregemm<<<dim3(BB * SS / 64, 13), 256, 0, stream>>>(x16, w16, bih_f, bhh_f,
                                                        bih_b, bhh_b, preF, preB);
  k_lstm<<<256, 832, 0, stream>>>(preF, preB, whh_f, whh_b, hbuf);
  k_proj<<<(BB * SS * NTAGS + 255) / 256, 256, 0, stream>>>(hbuf, proj_w, proj_b, em);
  k_score<<<BB, 64, 0, stream>>>(em, trans, y, mask, scoreY);
  k_crf<<<BB / 2, 64, 0, stream>>>(em, trans, mask, scoreY, out);
}

// Round 14
// 613.021 us; speedup vs baseline: 1.3225x; 1.0060x over previous
//
#include <hip/hip_runtime.h>
#include <hip/hip_fp16.h>
#include <cstdint>
#include <cstddef>

#define BB 128
#define SS 256
#define LL 10
#define NTAGS 32
#define TAG_START 30
#define TAG_END 31
#define WDIM 100
#define CDIM 30
#define NFILT 30
#define HDIM 100
#define KIN 130      // LSTM_IN = WDIM + FILT
#define KPAD 160     // padded K for f16 GEMM operands
#define GDIM 400     // 4*H
#define NROWS 832    // 13*64 padded W rows
#define NEGV -10000.0f
#define CTOK 8       // tokens per charconv block

typedef _Float16 h2 __attribute__((ext_vector_type(2)));
typedef _Float16 f16x8 __attribute__((ext_vector_type(8)));
typedef float f32x4 __attribute__((ext_vector_type(4)));

__device__ __forceinline__ float sigm(float x) { return 1.0f / (1.0f + __expf(-x)); }
__device__ __forceinline__ float tanh_fast(float x) { return 2.0f / (1.0f + __expf(-2.0f * x)) - 1.0f; }

// ---------------- K1a: word embedding gather -> x16[:, 0:100], zero pad [130:160) ----------------
__global__ void k_word(const float* __restrict__ wemb, const int* __restrict__ wx,
                       _Float16* __restrict__ x16) {
  int idx = blockIdx.x * blockDim.x + threadIdx.x;
  if (idx >= BB * SS * KPAD) return;
  int token = idx / KPAD;
  int d = idx - token * KPAD;
  if (d < WDIM) {
    x16[idx] = (_Float16)wemb[(size_t)wx[token] * WDIM + d];
  } else if (d >= KIN) {
    x16[idx] = (_Float16)0.f;
  }
}

// ---------------- K1b: char conv + max-pool -> x16[:, 100:130] ----------------
__global__ __launch_bounds__(256) void k_charconv(const float* __restrict__ cemb,
                                                  const float* __restrict__ convw,
                                                  const float* __restrict__ convb,
                                                  const int* __restrict__ cx,
                                                  _Float16* __restrict__ x16) {
  int blk = blockIdx.x;
  int tid = threadIdx.x;
  int tok8 = tid >> 5;
  int f = tid & 31;
  int token0 = blk * CTOK;
  __shared__ float e[CTOK][LL * CDIM];
  __shared__ int ci[CTOK][LL];
  if (tid < CTOK * LL) {
    int t = tid / LL, l = tid - t * LL;
    ci[t][l] = cx[(token0 + t) * LL + l];
  }
  __syncthreads();
  for (int i = tid; i < CTOK * LL * CDIM; i += 256) {
    int t = i / (LL * CDIM);
    int r = i - t * (LL * CDIM);
    int l = r / CDIM, c = r - l * CDIM;
    e[t][l * CDIM + c] = cemb[ci[t][l] * CDIM + c];
  }
  __syncthreads();
  if (f < NFILT) {
    float d0[LL], d1[LL], d2[LL];
#pragma unroll
    for (int l = 0; l < LL; l++) { d0[l] = 0.f; d1[l] = 0.f; d2[l] = 0.f; }
    const float* et = &e[tok8][0];
    for (int c = 0; c < CDIM; c++) {
      float w0 = convw[(f * 3 + 0) * CDIM + c];
      float w1 = convw[(f * 3 + 1) * CDIM + c];
      float w2 = convw[(f * 3 + 2) * CDIM + c];
#pragma unroll
      for (int l = 0; l < LL; l++) {
        float ev = et[l * CDIM + c];
        d0[l] += ev * w0; d1[l] += ev * w1; d2[l] += ev * w2;
      }
    }
    float bias = convb[f];
    float m = -3.0e38f;
#pragma unroll
    for (int h = 0; h < LL + 2; h++) {
      float acc = bias;
      int j0 = h - 2, j1 = h - 1, j2 = h;
      if (j0 >= 0 && j0 < LL) acc += d0[j0];
      if (j1 >= 0 && j1 < LL) acc += d1[j1];
      if (j2 >= 0 && j2 < LL) acc += d2[j2];
      m = fmaxf(m, acc);
    }
    x16[(size_t)(token0 + tok8) * KPAD + WDIM + f] = (_Float16)m;
  }
}

// ---------------- K1c: W (wih_f | wih_b) -> f16 [832][160], padded zeros ----------------
__global__ void k_wcvt(const float* __restrict__ wihF, const float* __restrict__ wihB,
                       _Float16* __restrict__ w16) {
  int idx = blockIdx.x * blockDim.x + threadIdx.x;
  if (idx >= NROWS * KPAD) return;
  int n = idx / KPAD;
  int k = idx - n * KPAD;
  float v = 0.f;
  if (k < KIN && n < 2 * GDIM) {
    v = (n < GDIM) ? wihF[(size_t)n * KIN + k] : wihB[(size_t)(n - GDIM) * KIN + k];
  }
  w16[idx] = (_Float16)v;
}

// ---------------- K2: pre = x @ wih^T + (bih+bhh), MFMA f16, f16 output ----------------
__global__ __launch_bounds__(256) void k_pregemm(
    const _Float16* __restrict__ x16, const _Float16* __restrict__ w16,
    const float* __restrict__ bihF, const float* __restrict__ bhhF,
    const float* __restrict__ bihB, const float* __restrict__ bhhB,
    _Float16* __restrict__ preF, _Float16* __restrict__ preB) {
  __shared__ __align__(16) _Float16 Asl[64 * 40];
  __shared__ __align__(16) _Float16 Bsl[64 * 40];
  int m0 = blockIdx.x * 64;
  int n0 = blockIdx.y * 64;
  int tid = threadIdx.x;
  int lane = tid & 63, w = tid >> 6;
  int quad = lane >> 4, l15 = lane & 15;

  f32x4 acc[4];
#pragma unroll
  for (int i = 0; i < 4; i++) acc[i] = (f32x4){0.f, 0.f, 0.f, 0.f};

  int r = tid >> 2;            // staging row 0..63
  int kk = (tid & 3) * 8;      // k offset within chunk
  const _Float16* xs = x16 + (size_t)(m0 + r) * KPAD + kk;
  const _Float16* wsrc = w16 + (size_t)(n0 + r) * KPAD + kk;

  for (int kc = 0; kc < 5; kc++) {
    if (kc) __syncthreads();
    *(f16x8*)&Asl[r * 40 + kk] = *(const f16x8*)(xs + kc * 32);
    *(f16x8*)&Bsl[r * 40 + kk] = *(const f16x8*)(wsrc + kc * 32);
    __syncthreads();

    f16x8 bfrag = *(const f16x8*)&Bsl[(w * 16 + l15) * 40 + quad * 8];
#pragma unroll
    for (int mt = 0; mt < 4; mt++) {
      f16x8 afrag = *(const f16x8*)&Asl[(mt * 16 + l15) * 40 + quad * 8];
      acc[mt] = __builtin_amdgcn_mfma_f32_16x16x32_f16(afrag, bfrag, acc[mt], 0, 0, 0);
    }
  }

  int ng = n0 + w * 16 + l15;  // this lane's output column (fixed)
  if (ng < 2 * GDIM) {
    int dir = ng >= GDIM;
    int jb = dir ? ng - GDIM : ng;
    _Float16* dst = dir ? preB : preF;
    float bias = (dir ? bihB : bihF)[jb] + (dir ? bhhB : bhhF)[jb];
#pragma unroll
    for (int mt = 0; mt < 4; mt++) {
#pragma unroll
      for (int i = 0; i < 4; i++) {
        int m = m0 + mt * 16 + quad * 4 + i;
        dst[(size_t)m * GDIM + jb] = (_Float16)(acc[mt][i] + bias);
      }
    }
  }
}

// ---------------- K3: recurrent LSTM scan, rpt=4 x ksplit=4, 448 threads ----------------
// R13 analysis: step cost = 91 h-broadcast b128 (13 waves x 7) + 2 barriers
// over 13 waves. LDS reads/step = 78/rows-per-thread (independent of ksplit),
// barrier cost scales with waves. This version: thread (rg<100, kg<4) owns
// 4 consecutive rows (4rg..4rg+3) x k-window [32kg,32kg+32). 448 threads =
// 7 waves: h-read 2 uint4/thread -> 14 b128/step (6.5x fewer), partials
// written as one float4, gate threads sum 4x4 partials. Weights 32 half2 =
// 32 VGPR (R2 proved 84-VGPR grant at 448 threads). Same f16 __hfma2 math
// class as R13 (absmax 0.0). Same 2-barrier skeleton.
__global__ __launch_bounds__(448) void k_lstm(
    const _Float16* __restrict__ preF, const _Float16* __restrict__ preB,
    const float* __restrict__ whhF, const float* __restrict__ whhB,
    _Float16* __restrict__ hbuf) {
  int blk = blockIdx.x;
  int dir = blk >> 7;   // 0 fwd, 1 bwd
  int b = blk & 127;
  const _Float16* pre = dir ? preB : preF;
  const float* whh = dir ? whhB : whhF;
  int tid = threadIdx.x;
  int kg = tid / 112;                  // 0..3 (and 4 for tid=448.. none)
  int rg = tid - kg * 112;
  bool act = (kg < 4) && (rg < 100);
  int r0 = act ? rg * 4 : 0;           // first of 4 consecutive rows
  int kb = (act ? kg : 0) * 32;        // k-window base (halves)

  // weights: 4 rows x 32 k as half2 -> 32 VGPRs
  __half2 wp[4][8];
  {
#pragma unroll
    for (int i = 0; i < 4; i++) {
      const float* wr = whh + (size_t)(r0 + i) * HDIM;
#pragma unroll
      for (int q = 0; q < 8; q++) {
        int k0 = kb + 2 * q;
        float w0 = (k0 < HDIM) ? wr[k0] : 0.f;
        float w1 = (k0 + 1 < HDIM) ? wr[k0 + 1] : 0.f;
        wp[i][q] = __floats2half2_rn(w0, w1);
      }
    }
  }

  __shared__ __align__(16) _Float16 hsh16[2][128];
  __shared__ __align__(16) float gpart[4][GDIM];
  if (tid < 128) { hsh16[0][tid] = (_Float16)0.f; hsh16[1][tid] = (_Float16)0.f; }
  float c = 0.f;

  // pre prefetch: kg==0 threads add pre[r0..r0+3]; 4 halves = one uint2 load
  const _Float16* pbase = pre + ((size_t)b * SS + (dir ? (SS - 1) : 0)) * GDIM + r0;
  const intptr_t pstep = dir ? -(intptr_t)GDIM : (intptr_t)GDIM;
  uint2 p0 = {0, 0}, p1 = {0, 0};
  if (act && kg == 0) {
    p0 = *(const uint2*)pbase;
    p1 = *(const uint2*)(pbase + pstep);
  }
  __syncthreads();

  int cur = 0;
  for (int step = 0; step < SS; step++) {
    uint2 p2 = {0, 0};
    if (act && kg == 0) {
      int tn = (step + 2 < SS) ? (step + 2) : (SS - 1);
      p2 = *(const uint2*)(pbase + (intptr_t)tn * pstep);
    }

    if (act) {
      const uint4* h4 = (const uint4*)&hsh16[cur][kb];
      uint4 hv0 = h4[0], hv1 = h4[1];
      __half2 hp[8];
      hp[0] = __builtin_bit_cast(__half2, hv0.x);
      hp[1] = __builtin_bit_cast(__half2, hv0.y);
      hp[2] = __builtin_bit_cast(__half2, hv0.z);
      hp[3] = __builtin_bit_cast(__half2, hv0.w);
      hp[4] = __builtin_bit_cast(__half2, hv1.x);
      hp[5] = __builtin_bit_cast(__half2, hv1.y);
      hp[6] = __builtin_bit_cast(__half2, hv1.z);
      hp[7] = __builtin_bit_cast(__half2, hv1.w);

      float racc[4];
      __half2 z = __floats2half2_rn(0.f, 0.f);
#pragma unroll
      for (int i = 0; i < 4; i++) {
        __half2 a0 = z, a1 = z;
#pragma unroll
        for (int q = 0; q < 8; q += 2) {
          a0 = __hfma2(wp[i][q], hp[q], a0);
          a1 = __hfma2(wp[i][q + 1], hp[q + 1], a1);
        }
        racc[i] = (__low2float(a0) + __high2float(a0)) +
                  (__low2float(a1) + __high2float(a1));
      }
      if (kg == 0) {
        __half2 pa = __builtin_bit_cast(__half2, p0.x);
        __half2 pbv = __builtin_bit_cast(__half2, p0.y);
        racc[0] += __low2float(pa);
        racc[1] += __high2float(pa);
        racc[2] += __low2float(pbv);
        racc[3] += __high2float(pbv);
      }
      *(f32x4*)&gpart[kg][r0] = (f32x4){racc[0], racc[1], racc[2], racc[3]};
    }
    __syncthreads();
    if (tid < HDIM) {
      int j = tid;
      float gi = (gpart[0][j] + gpart[1][j]) + (gpart[2][j] + gpart[3][j]);
      float gf = (gpart[0][j + HDIM] + gpart[1][j + HDIM]) + (gpart[2][j + HDIM] + gpart[3][j + HDIM]);
      float gg = (gpart[0][j + 2 * HDIM] + gpart[1][j + 2 * HDIM]) + (gpart[2][j + 2 * HDIM] + gpart[3][j + 2 * HDIM]);
      float go = (gpart[0][j + 3 * HDIM] + gpart[1][j + 3 * HDIM]) + (gpart[2][j + 3 * HDIM] + gpart[3][j + 3 * HDIM]);
      float ig = sigm(gi), fg = sigm(gf), g2 = tanh_fast(gg), og = sigm(go);
      c = fg * c + ig * g2;
      float h = og * tanh_fast(c);
      hsh16[cur ^ 1][j] = (_Float16)h;
      int t = dir ? (SS - 1 - step) : step;
      hbuf[((size_t)b * SS + t) * (2 * HDIM) + dir * HDIM + j] = (_Float16)h;
    }
    __syncthreads();
    p0 = p1; p1 = p2;
    cur ^= 1;
  }
}

// ---------------- K4: emission = [h_f,h_b] @ proj_w^T + proj_b ----------------
__global__ void k_proj(const _Float16* __restrict__ hbuf, const float* __restrict__ pw,
                       const float* __restrict__ pb, float* __restrict__ em) {
  int idx = blockIdx.x * blockDim.x + threadIdx.x;  // token*32 + tag
  if (idx >= BB * SS * NTAGS) return;
  int token = idx >> 5, tag = idx & 31;
  const uint4* h4 = (const uint4*)(hbuf + (size_t)token * 2 * HDIM);
  const float* wrow = pw + (size_t)tag * 2 * HDIM;
  float acc = pb[tag];
#pragma unroll
  for (int k = 0; k < 25; k++) {
    uint4 hv = h4[k];
    h2 a = __builtin_bit_cast(h2, hv.x);
    h2 bq = __builtin_bit_cast(h2, hv.y);
    h2 cq = __builtin_bit_cast(h2, hv.z);
    h2 d = __builtin_bit_cast(h2, hv.w);
    const float4* w4 = (const float4*)(wrow + k * 8);
    float4 w0 = w4[0], w1 = w4[1];
    acc += (float)a.x * w0.x + (float)a.y * w0.y + (float)bq.x * w0.z + (float)bq.y * w0.w
         + (float)cq.x * w1.x + (float)cq.y * w1.y + (float)d.x * w1.z + (float)d.y * w1.w;
  }
  em[idx] = acc;
}

// ---------------- K5: gold path score per batch ----------------
__global__ __launch_bounds__(64) void k_score(const float* __restrict__ em,
                                              const float* __restrict__ trans,
                                              const int* __restrict__ y,
                                              const int* __restrict__ mask,
                                              float* __restrict__ scoreY) {
  int b = blockIdx.x, l = threadIdx.x;
  float acc = 0.f;
  for (int s = l; s < SS; s += 64) {
    int curt = y[b * SS + s];
    int prevt = (s == 0) ? TAG_START : y[b * SS + s - 1];
    float mk = (float)mask[b * SS + s];
    acc += (em[((size_t)b * SS + s) * NTAGS + curt] + trans[prevt * NTAGS + curt]) * mk;
  }
#pragma unroll
  for (int off = 32; off > 0; off >>= 1) acc += __shfl_down(acc, off);
  if (l == 0) scoreY[b] = acc + trans[y[b * SS + SS - 1] * NTAGS + TAG_END];
}

// ---------------- K6: CRF forward (partition function) + loss ----------------
__global__ __launch_bounds__(64) void k_crf(const float* __restrict__ em,
                                            const float* __restrict__ trans,
                                            const int* __restrict__ mask,
                                            const float* __restrict__ scoreY,
                                            float* __restrict__ out) {
  int g = threadIdx.x >> 5;
  int j = threadIdx.x & 31;
  int b = blockIdx.x * 2 + g;
  float tcol[NTAGS];
#pragma unroll
  for (int i = 0; i < NTAGS; i++) tcol[i] = trans[i * NTAGS + j];
  float la = (j == TAG_START) ? 0.f : NEGV;
  __shared__ float lash[2][NTAGS];

  const float* emb = em + (size_t)b * SS * NTAGS + j;
  const int* mkb = mask + b * SS;
  float e0 = emb[0], e1 = emb[NTAGS];
  int m0i = mkb[0], m1i = mkb[1];

  for (int s = 0; s < SS; s++) {
    int sn = (s + 2 < SS) ? (s + 2) : (SS - 1);
    float e2 = emb[(size_t)sn * NTAGS];
    int m2i = mkb[sn];

    lash[g][j] = la;
    __syncthreads();
    float m = -3.0e38f;
#pragma unroll
    for (int i = 0; i < NTAGS; i++) m = fmaxf(m, lash[g][i] + tcol[i]);
    float sum = 0.f;
#pragma unroll
    for (int i = 0; i < NTAGS; i++) sum += __expf(lash[g][i] + tcol[i] - m);
    float la2 = m + __logf(sum) + e0;
    float mk = (float)m0i;
    la = la2 * mk + la * (1.f - mk);
    __syncthreads();
    e0 = e1; e1 = e2; m0i = m1i; m1i = m2i;
  }
  la += trans[j * NTAGS + TAG_END];
  lash[g][j] = la;
  __syncthreads();
  float m = -3.0e38f;
#pragma unroll
  for (int i = 0; i < NTAGS; i++) m = fmaxf(m, lash[g][i]);
  float sum = 0.f;
#pragma unroll
  for (int i = 0; i < NTAGS; i++) sum += __expf(lash[g][i] - m);
  float total = m + __logf(sum);
  if (j == 0) atomicAdd(out, (total - scoreY[b]) * (1.0f / BB));
}

extern "C" void kernel_launch(void* const* d_in, const int* in_sizes, int n_in,
                              void* d_out, int out_size, void* d_ws, size_t ws_size,
                              hipStream_t stream) {
  const float* word_emb = (const float*)d_in[0];
  const float* char_emb = (const float*)d_in[1];
  const float* conv_w   = (const float*)d_in[2];
  const float* conv_b   = (const float*)d_in[3];
  const float* wih_f    = (const float*)d_in[4];
  const float* whh_f    = (const float*)d_in[5];
  const float* bih_f    = (const float*)d_in[6];
  const float* bhh_f    = (const float*)d_in[7];
  const float* wih_b    = (const float*)d_in[8];
  const float* whh_b    = (const float*)d_in[9];
  const float* bih_b    = (const float*)d_in[10];
  const float* bhh_b    = (const float*)d_in[11];
  const float* proj_w   = (const float*)d_in[12];
  const float* proj_b   = (const float*)d_in[13];
  const float* trans    = (const float*)d_in[14];
  const int* word_x     = (const int*)d_in[15];
  const int* char_x     = (const int*)d_in[16];
  const int* y          = (const int*)d_in[17];
  const int* mask       = (const int*)d_in[18];
  float* out = (float*)d_out;

  _Float16* x16   = (_Float16*)d_ws;                     // 32768*160 halves
  _Float16* w16   = x16 + (size_t)BB * SS * KPAD;        // 832*160 halves
  _Float16* preF  = w16 + (size_t)NROWS * KPAD;          // 32768*400 halves
  _Float16* preB  = preF + (size_t)BB * SS * GDIM;       // 32768*400 halves
  _Float16* hbuf  = preB + (size_t)BB * SS * GDIM;       // 32768*200 halves
  float* em       = (float*)(hbuf + (size_t)BB * SS * 2 * HDIM);  // 32768*32 f32
  float* scoreY   = em + (size_t)BB * SS * NTAGS;        // 128

  hipMemsetAsync(d_out, 0, sizeof(float), stream);
  k_word<<<(BB * SS * KPAD + 255) / 256, 256, 0, stream>>>(word_emb, word_x, x16);
  k_charconv<<<BB * SS / CTOK, 256, 0, stream>>>(char_emb, conv_w, conv_b, char_x, x16);
  k_wcvt<<<(NROWS * KPAD + 255) / 256, 256, 0, stream>>>(wih_f, wih_b, w16);
  k_pregemm<<<dim3(BB * SS / 64, 13), 256, 0, stream>>>(x16, w16, bih_f, bhh_f,
                                                        bih_b, bhh_b, preF, preB);
  k_lstm<<<256, 448, 0, stream>>>(preF, preB, whh_f, whh_b, hbuf);
  k_proj<<<(BB * SS * NTAGS + 255) / 256, 256, 0, stream>>>(hbuf, proj_w, proj_b, em);
  k_score<<<BB, 64, 0, stream>>>(em, trans, y, mask, scoreY);
  k_crf<<<BB / 2, 64, 0, stream>>>(em, trans, mask, scoreY, out);
}

// Round 15
// 595.322 us; speedup vs baseline: 1.3619x; 1.0297x over previous
//
#include <hip/hip_runtime.h>
#include <hip/hip_fp16.h>
#include <cstdint>
#include <cstddef>

#define BB 128
#define SS 256
#define LL 10
#define NTAGS 32
#define TAG_START 30
#define TAG_END 31
#define WDIM 100
#define CDIM 30
#define NFILT 30
#define HDIM 100
#define KIN 130      // LSTM_IN = WDIM + FILT
#define KPAD 160     // padded K for f16 GEMM operands
#define GDIM 400     // 4*H
#define NROWS 832    // 13*64 padded W rows
#define NEGV -10000.0f
#define CTOK 8       // tokens per charconv block

typedef _Float16 h2 __attribute__((ext_vector_type(2)));
typedef _Float16 f16x8 __attribute__((ext_vector_type(8)));
typedef float f32x4 __attribute__((ext_vector_type(4)));

__device__ __forceinline__ float sigm(float x) { return 1.0f / (1.0f + __expf(-x)); }
__device__ __forceinline__ float tanh_fast(float x) { return 2.0f / (1.0f + __expf(-2.0f * x)) - 1.0f; }

// Barrier that only drains LDS (lgkmcnt), leaving global ops (vmcnt) in
// flight. __syncthreads() emits s_waitcnt vmcnt(0) which drains the p2 HBM
// prefetch (~700 cyc) and the hbuf store-ack (~300 cyc) EVERY step — R14
// counters (VALUBusy 31%, step ~2150 cyc, LDS-read cut neutral) indict these
// drains as the dominant residual. All cross-thread traffic here is LDS, so
// lgkmcnt(0)+s_barrier is sufficient. This barrier passed in R2; the R3/R4
// NaNs shared __launch_bounds__(,2) as common factor (R4 NaN'd WITHOUT this
// barrier), so it has one pass and zero clean failures.
__device__ __forceinline__ void barrier_lds_only() {
  asm volatile("s_waitcnt lgkmcnt(0)" ::: "memory");
  __builtin_amdgcn_s_barrier();
  asm volatile("" ::: "memory");
}

// ---------------- K1a: word embedding gather -> x16[:, 0:100], zero pad [130:160) ----------------
__global__ void k_word(const float* __restrict__ wemb, const int* __restrict__ wx,
                       _Float16* __restrict__ x16) {
  int idx = blockIdx.x * blockDim.x + threadIdx.x;
  if (idx >= BB * SS * KPAD) return;
  int token = idx / KPAD;
  int d = idx - token * KPAD;
  if (d < WDIM) {
    x16[idx] = (_Float16)wemb[(size_t)wx[token] * WDIM + d];
  } else if (d >= KIN) {
    x16[idx] = (_Float16)0.f;
  }
}

// ---------------- K1b: char conv + max-pool -> x16[:, 100:130] ----------------
__global__ __launch_bounds__(256) void k_charconv(const float* __restrict__ cemb,
                                                  const float* __restrict__ convw,
                                                  const float* __restrict__ convb,
                                                  const int* __restrict__ cx,
                                                  _Float16* __restrict__ x16) {
  int blk = blockIdx.x;
  int tid = threadIdx.x;
  int tok8 = tid >> 5;
  int f = tid & 31;
  int token0 = blk * CTOK;
  __shared__ float e[CTOK][LL * CDIM];
  __shared__ int ci[CTOK][LL];
  if (tid < CTOK * LL) {
    int t = tid / LL, l = tid - t * LL;
    ci[t][l] = cx[(token0 + t) * LL + l];
  }
  __syncthreads();
  for (int i = tid; i < CTOK * LL * CDIM; i += 256) {
    int t = i / (LL * CDIM);
    int r = i - t * (LL * CDIM);
    int l = r / CDIM, c = r - l * CDIM;
    e[t][l * CDIM + c] = cemb[ci[t][l] * CDIM + c];
  }
  __syncthreads();
  if (f < NFILT) {
    float d0[LL], d1[LL], d2[LL];
#pragma unroll
    for (int l = 0; l < LL; l++) { d0[l] = 0.f; d1[l] = 0.f; d2[l] = 0.f; }
    const float* et = &e[tok8][0];
    for (int c = 0; c < CDIM; c++) {
      float w0 = convw[(f * 3 + 0) * CDIM + c];
      float w1 = convw[(f * 3 + 1) * CDIM + c];
      float w2 = convw[(f * 3 + 2) * CDIM + c];
#pragma unroll
      for (int l = 0; l < LL; l++) {
        float ev = et[l * CDIM + c];
        d0[l] += ev * w0; d1[l] += ev * w1; d2[l] += ev * w2;
      }
    }
    float bias = convb[f];
    float m = -3.0e38f;
#pragma unroll
    for (int h = 0; h < LL + 2; h++) {
      float acc = bias;
      int j0 = h - 2, j1 = h - 1, j2 = h;
      if (j0 >= 0 && j0 < LL) acc += d0[j0];
      if (j1 >= 0 && j1 < LL) acc += d1[j1];
      if (j2 >= 0 && j2 < LL) acc += d2[j2];
      m = fmaxf(m, acc);
    }
    x16[(size_t)(token0 + tok8) * KPAD + WDIM + f] = (_Float16)m;
  }
}

// ---------------- K1c: W (wih_f | wih_b) -> f16 [832][160], padded zeros ----------------
__global__ void k_wcvt(const float* __restrict__ wihF, const float* __restrict__ wihB,
                       _Float16* __restrict__ w16) {
  int idx = blockIdx.x * blockDim.x + threadIdx.x;
  if (idx >= NROWS * KPAD) return;
  int n = idx / KPAD;
  int k = idx - n * KPAD;
  float v = 0.f;
  if (k < KIN && n < 2 * GDIM) {
    v = (n < GDIM) ? wihF[(size_t)n * KIN + k] : wihB[(size_t)(n - GDIM) * KIN + k];
  }
  w16[idx] = (_Float16)v;
}

// ---------------- K2: pre = x @ wih^T + (bih+bhh), MFMA f16, f16 output ----------------
__global__ __launch_bounds__(256) void k_pregemm(
    const _Float16* __restrict__ x16, const _Float16* __restrict__ w16,
    const float* __restrict__ bihF, const float* __restrict__ bhhF,
    const float* __restrict__ bihB, const float* __restrict__ bhhB,
    _Float16* __restrict__ preF, _Float16* __restrict__ preB) {
  __shared__ __align__(16) _Float16 Asl[64 * 40];
  __shared__ __align__(16) _Float16 Bsl[64 * 40];
  int m0 = blockIdx.x * 64;
  int n0 = blockIdx.y * 64;
  int tid = threadIdx.x;
  int lane = tid & 63, w = tid >> 6;
  int quad = lane >> 4, l15 = lane & 15;

  f32x4 acc[4];
#pragma unroll
  for (int i = 0; i < 4; i++) acc[i] = (f32x4){0.f, 0.f, 0.f, 0.f};

  int r = tid >> 2;            // staging row 0..63
  int kk = (tid & 3) * 8;      // k offset within chunk
  const _Float16* xs = x16 + (size_t)(m0 + r) * KPAD + kk;
  const _Float16* wsrc = w16 + (size_t)(n0 + r) * KPAD + kk;

  for (int kc = 0; kc < 5; kc++) {
    if (kc) __syncthreads();
    *(f16x8*)&Asl[r * 40 + kk] = *(const f16x8*)(xs + kc * 32);
    *(f16x8*)&Bsl[r * 40 + kk] = *(const f16x8*)(wsrc + kc * 32);
    __syncthreads();

    f16x8 bfrag = *(const f16x8*)&Bsl[(w * 16 + l15) * 40 + quad * 8];
#pragma unroll
    for (int mt = 0; mt < 4; mt++) {
      f16x8 afrag = *(const f16x8*)&Asl[(mt * 16 + l15) * 40 + quad * 8];
      acc[mt] = __builtin_amdgcn_mfma_f32_16x16x32_f16(afrag, bfrag, acc[mt], 0, 0, 0);
    }
  }

  int ng = n0 + w * 16 + l15;  // this lane's output column (fixed)
  if (ng < 2 * GDIM) {
    int dir = ng >= GDIM;
    int jb = dir ? ng - GDIM : ng;
    _Float16* dst = dir ? preB : preF;
    float bias = (dir ? bihB : bihF)[jb] + (dir ? bhhB : bhhF)[jb];
#pragma unroll
    for (int mt = 0; mt < 4; mt++) {
#pragma unroll
      for (int i = 0; i < 4; i++) {
        int m = m0 + mt * 16 + quad * 4 + i;
        dst[(size_t)m * GDIM + jb] = (_Float16)(acc[mt][i] + bias);
      }
    }
  }
}

// ---------------- K3: recurrent LSTM scan, rpt=4 x ksplit=4, 448 threads ----------------
// R14 structure (proven, absmax 0.0, VGPR 44) with ONE delta: the two in-loop
// __syncthreads are replaced by lgkm-only barriers so the p2 HBM prefetch and
// hbuf global store stay in flight across barriers instead of being drained
// (~1000 cyc/step of vmcnt(0) waits per the R14 counter decomposition).
__global__ __launch_bounds__(448) void k_lstm(
    const _Float16* __restrict__ preF, const _Float16* __restrict__ preB,
    const float* __restrict__ whhF, const float* __restrict__ whhB,
    _Float16* __restrict__ hbuf) {
  int blk = blockIdx.x;
  int dir = blk >> 7;   // 0 fwd, 1 bwd
  int b = blk & 127;
  const _Float16* pre = dir ? preB : preF;
  const float* whh = dir ? whhB : whhF;
  int tid = threadIdx.x;
  int kg = tid / 112;                  // 0..3
  int rg = tid - kg * 112;
  bool act = (kg < 4) && (rg < 100);
  int r0 = act ? rg * 4 : 0;           // first of 4 consecutive rows
  int kb = (act ? kg : 0) * 32;        // k-window base (halves)

  // weights: 4 rows x 32 k as half2 -> 32 VGPRs
  __half2 wp[4][8];
  {
#pragma unroll
    for (int i = 0; i < 4; i++) {
      const float* wr = whh + (size_t)(r0 + i) * HDIM;
#pragma unroll
      for (int q = 0; q < 8; q++) {
        int k0 = kb + 2 * q;
        float w0 = (k0 < HDIM) ? wr[k0] : 0.f;
        float w1 = (k0 + 1 < HDIM) ? wr[k0 + 1] : 0.f;
        wp[i][q] = __floats2half2_rn(w0, w1);
      }
    }
  }

  __shared__ __align__(16) _Float16 hsh16[2][128];
  __shared__ __align__(16) float gpart[4][GDIM];
  if (tid < 128) { hsh16[0][tid] = (_Float16)0.f; hsh16[1][tid] = (_Float16)0.f; }
  float c = 0.f;

  const _Float16* pbase = pre + ((size_t)b * SS + (dir ? (SS - 1) : 0)) * GDIM + r0;
  const intptr_t pstep = dir ? -(intptr_t)GDIM : (intptr_t)GDIM;
  uint2 p0 = {0, 0}, p1 = {0, 0};
  if (act && kg == 0) {
    p0 = *(const uint2*)pbase;
    p1 = *(const uint2*)(pbase + pstep);
  }
  __syncthreads();

  int cur = 0;
  for (int step = 0; step < SS; step++) {
    uint2 p2 = {0, 0};
    if (act && kg == 0) {
      int tn = (step + 2 < SS) ? (step + 2) : (SS - 1);
      p2 = *(const uint2*)(pbase + (intptr_t)tn * pstep);
    }

    if (act) {
      const uint4* h4 = (const uint4*)&hsh16[cur][kb];
      uint4 hv0 = h4[0], hv1 = h4[1];
      __half2 hp[8];
      hp[0] = __builtin_bit_cast(__half2, hv0.x);
      hp[1] = __builtin_bit_cast(__half2, hv0.y);
      hp[2] = __builtin_bit_cast(__half2, hv0.z);
      hp[3] = __builtin_bit_cast(__half2, hv0.w);
      hp[4] = __builtin_bit_cast(__half2, hv1.x);
      hp[5] = __builtin_bit_cast(__half2, hv1.y);
      hp[6] = __builtin_bit_cast(__half2, hv1.z);
      hp[7] = __builtin_bit_cast(__half2, hv1.w);

      float racc[4];
      __half2 z = __floats2half2_rn(0.f, 0.f);
#pragma unroll
      for (int i = 0; i < 4; i++) {
        __half2 a0 = z, a1 = z;
#pragma unroll
        for (int q = 0; q < 8; q += 2) {
          a0 = __hfma2(wp[i][q], hp[q], a0);
          a1 = __hfma2(wp[i][q + 1], hp[q + 1], a1);
        }
        racc[i] = (__low2float(a0) + __high2float(a0)) +
                  (__low2float(a1) + __high2float(a1));
      }
      if (kg == 0) {
        __half2 pa = __builtin_bit_cast(__half2, p0.x);
        __half2 pbv = __builtin_bit_cast(__half2, p0.y);
        racc[0] += __low2float(pa);
        racc[1] += __high2float(pa);
        racc[2] += __low2float(pbv);
        racc[3] += __high2float(pbv);
      }
      *(f32x4*)&gpart[kg][r0] = (f32x4){racc[0], racc[1], racc[2], racc[3]};
    }
    barrier_lds_only();
    if (tid < HDIM) {
      int j = tid;
      float gi = (gpart[0][j] + gpart[1][j]) + (gpart[2][j] + gpart[3][j]);
      float gf = (gpart[0][j + HDIM] + gpart[1][j + HDIM]) + (gpart[2][j + HDIM] + gpart[3][j + HDIM]);
      float gg = (gpart[0][j + 2 * HDIM] + gpart[1][j + 2 * HDIM]) + (gpart[2][j + 2 * HDIM] + gpart[3][j + 2 * HDIM]);
      float go = (gpart[0][j + 3 * HDIM] + gpart[1][j + 3 * HDIM]) + (gpart[2][j + 3 * HDIM] + gpart[3][j + 3 * HDIM]);
      float ig = sigm(gi), fg = sigm(gf), g2 = tanh_fast(gg), og = sigm(go);
      c = fg * c + ig * g2;
      float h = og * tanh_fast(c);
      hsh16[cur ^ 1][j] = (_Float16)h;
      int t = dir ? (SS - 1 - step) : step;
      hbuf[((size_t)b * SS + t) * (2 * HDIM) + dir * HDIM + j] = (_Float16)h;
    }
    barrier_lds_only();
    p0 = p1; p1 = p2;
    cur ^= 1;
  }
}

// ---------------- K4: emission = [h_f,h_b] @ proj_w^T + proj_b ----------------
__global__ void k_proj(const _Float16* __restrict__ hbuf, const float* __restrict__ pw,
                       const float* __restrict__ pb, float* __restrict__ em) {
  int idx = blockIdx.x * blockDim.x + threadIdx.x;  // token*32 + tag
  if (idx >= BB * SS * NTAGS) return;
  int token = idx >> 5, tag = idx & 31;
  const uint4* h4 = (const uint4*)(hbuf + (size_t)token * 2 * HDIM);
  const float* wrow = pw + (size_t)tag * 2 * HDIM;
  float acc = pb[tag];
#pragma unroll
  for (int k = 0; k < 25; k++) {
    uint4 hv = h4[k];
    h2 a = __builtin_bit_cast(h2, hv.x);
    h2 bq = __builtin_bit_cast(h2, hv.y);
    h2 cq = __builtin_bit_cast(h2, hv.z);
    h2 d = __builtin_bit_cast(h2, hv.w);
    const float4* w4 = (const float4*)(wrow + k * 8);
    float4 w0 = w4[0], w1 = w4[1];
    acc += (float)a.x * w0.x + (float)a.y * w0.y + (float)bq.x * w0.z + (float)bq.y * w0.w
         + (float)cq.x * w1.x + (float)cq.y * w1.y + (float)d.x * w1.z + (float)d.y * w1.w;
  }
  em[idx] = acc;
}

// ---------------- K5: gold path score per batch ----------------
__global__ __launch_bounds__(64) void k_score(const float* __restrict__ em,
                                              const float* __restrict__ trans,
                                              const int* __restrict__ y,
                                              const int* __restrict__ mask,
                                              float* __restrict__ scoreY) {
  int b = blockIdx.x, l = threadIdx.x;
  float acc = 0.f;
  for (int s = l; s < SS; s += 64) {
    int curt = y[b * SS + s];
    int prevt = (s == 0) ? TAG_START : y[b * SS + s - 1];
    float mk = (float)mask[b * SS + s];
    acc += (em[((size_t)b * SS + s) * NTAGS + curt] + trans[prevt * NTAGS + curt]) * mk;
  }
#pragma unroll
  for (int off = 32; off > 0; off >>= 1) acc += __shfl_down(acc, off);
  if (l == 0) scoreY[b] = acc + trans[y[b * SS + SS - 1] * NTAGS + TAG_END];
}

// ---------------- K6: CRF forward (partition function) + loss ----------------
__global__ __launch_bounds__(64) void k_crf(const float* __restrict__ em,
                                            const float* __restrict__ trans,
                                            const int* __restrict__ mask,
                                            const float* __restrict__ scoreY,
                                            float* __restrict__ out) {
  int g = threadIdx.x >> 5;
  int j = threadIdx.x & 31;
  int b = blockIdx.x * 2 + g;
  float tcol[NTAGS];
#pragma unroll
  for (int i = 0; i < NTAGS; i++) tcol[i] = trans[i * NTAGS + j];
  float la = (j == TAG_START) ? 0.f : NEGV;
  __shared__ float lash[2][NTAGS];

  const float* emb = em + (size_t)b * SS * NTAGS + j;
  const int* mkb = mask + b * SS;
  float e0 = emb[0], e1 = emb[NTAGS];
  int m0i = mkb[0], m1i = mkb[1];

  for (int s = 0; s < SS; s++) {
    int sn = (s + 2 < SS) ? (s + 2) : (SS - 1);
    float e2 = emb[(size_t)sn * NTAGS];
    int m2i = mkb[sn];

    lash[g][j] = la;
    __syncthreads();
    float m = -3.0e38f;
#pragma unroll
    for (int i = 0; i < NTAGS; i++) m = fmaxf(m, lash[g][i] + tcol[i]);
    float sum = 0.f;
#pragma unroll
    for (int i = 0; i < NTAGS; i++) sum += __expf(lash[g][i] + tcol[i] - m);
    float la2 = m + __logf(sum) + e0;
    float mk = (float)m0i;
    la = la2 * mk + la * (1.f - mk);
    __syncthreads();
    e0 = e1; e1 = e2; m0i = m1i; m1i = m2i;
  }
  la += trans[j * NTAGS + TAG_END];
  lash[g][j] = la;
  __syncthreads();
  float m = -3.0e38f;
#pragma unroll
  for (int i = 0; i < NTAGS; i++) m = fmaxf(m, lash[g][i]);
  float sum = 0.f;
#pragma unroll
  for (int i = 0; i < NTAGS; i++) sum += __expf(lash[g][i] - m);
  float total = m + __logf(sum);
  if (j == 0) atomicAdd(out, (total - scoreY[b]) * (1.0f / BB));
}

extern "C" void kernel_launch(void* const* d_in, const int* in_sizes, int n_in,
                              void* d_out, int out_size, void* d_ws, size_t ws_size,
                              hipStream_t stream) {
  const float* word_emb = (const float*)d_in[0];
  const float* char_emb = (const float*)d_in[1];
  const float* conv_w   = (const float*)d_in[2];
  const float* conv_b   = (const float*)d_in[3];
  const float* wih_f    = (const float*)d_in[4];
  const float* whh_f    = (const float*)d_in[5];
  const float* bih_f    = (const float*)d_in[6];
  const float* bhh_f    = (const float*)d_in[7];
  const float* wih_b    = (const float*)d_in[8];
  const float* whh_b    = (const float*)d_in[9];
  const float* bih_b    = (const float*)d_in[10];
  const float* bhh_b    = (const float*)d_in[11];
  const float* proj_w   = (const float*)d_in[12];
  const float* proj_b   = (const float*)d_in[13];
  const float* trans    = (const float*)d_in[14];
  const int* word_x     = (const int*)d_in[15];
  const int* char_x     = (const int*)d_in[16];
  const int* y          = (const int*)d_in[17];
  const int* mask       = (const int*)d_in[18];
  float* out = (float*)d_out;

  _Float16* x16   = (_Float16*)d_ws;                     // 32768*160 halves
  _Float16* w16   = x16 + (size_t)BB * SS * KPAD;        // 832*160 halves
  _Float16* preF  = w16 + (size_t)NROWS * KPAD;          // 32768*400 halves
  _Float16* preB  = preF + (size_t)BB * SS * GDIM;       // 32768*400 halves
  _Float16* hbuf  = preB + (size_t)BB * SS * GDIM;       // 32768*200 halves
  float* em       = (float*)(hbuf + (size_t)BB * SS * 2 * HDIM);  // 32768*32 f32
  float* scoreY   = em + (size_t)BB * SS * NTAGS;        // 128

  hipMemsetAsync(d_out, 0, sizeof(float), stream);
  k_word<<<(BB * SS * KPAD + 255) / 256, 256, 0, stream>>>(word_emb, word_x, x16);
  k_charconv<<<BB * SS / CTOK, 256, 0, stream>>>(char_emb, conv_w, conv_b, char_x, x16);
  k_wcvt<<<(NROWS * KPAD + 255) / 256, 256, 0, stream>>>(wih_f, wih_b, w16);
  k_pregemm<<<dim3(BB * SS / 64, 13), 256, 0, stream>>>(x16, w16, bih_f, bhh_f,
                                                        bih_b, bhh_b, preF, preB);
  k_lstm<<<256, 448, 0, stream>>>(preF, preB, whh_f, whh_b, hbuf);
  k_proj<<<(BB * SS * NTAGS + 255) / 256, 256, 0, stream>>>(hbuf, proj_w, proj_b, em);
  k_score<<<BB, 64, 0, stream>>>(em, trans, y, mask, scoreY);
  k_crf<<<BB / 2, 64, 0, stream>>>(em, trans, mask, scoreY, out);
}

// Round 16
// 588.765 us; speedup vs baseline: 1.3770x; 1.0111x over previous
//
#include <hip/hip_runtime.h>
#include <hip/hip_fp16.h>
#include <cstdint>
#include <cstddef>

#define BB 128
#define SS 256
#define LL 10
#define NTAGS 32
#define TAG_START 30
#define TAG_END 31
#define WDIM 100
#define CDIM 30
#define NFILT 30
#define HDIM 100
#define KIN 130      // LSTM_IN = WDIM + FILT
#define KPAD 160     // padded K for f16 GEMM operands
#define GDIM 400     // 4*H
#define NROWS 832    // 13*64 padded W rows
#define NEGV -10000.0f
#define CTOK 8       // tokens per charconv block

// fused-pre block ranges
#define NB_CONV (BB * SS / CTOK)               // 4096
#define NB_WORD (BB * SS * KPAD / 256)         // 20480
#define NB_WCVT (NROWS * KPAD / 256)           // 520
#define NB_PRE  (NB_CONV + NB_WORD + NB_WCVT)  // 25096

typedef _Float16 h2 __attribute__((ext_vector_type(2)));
typedef _Float16 f16x8 __attribute__((ext_vector_type(8)));
typedef float f32x4 __attribute__((ext_vector_type(4)));

__device__ __forceinline__ float sigm(float x) { return 1.0f / (1.0f + __expf(-x)); }
__device__ __forceinline__ float tanh_fast(float x) { return 2.0f / (1.0f + __expf(-2.0f * x)) - 1.0f; }

// lgkm-only barrier (R15-proven): leaves global prefetch/store in flight.
__device__ __forceinline__ void barrier_lds_only() {
  asm volatile("s_waitcnt lgkmcnt(0)" ::: "memory");
  __builtin_amdgcn_s_barrier();
  asm volatile("" ::: "memory");
}

// ---------------- K1 fused: charconv | word gather | wcvt, by block range ----------------
// Node-count reduction: non-lstm wall time has been pinned at ~385 us across
// R13-R15 while the bottom-up kernel model sums to ~200 us — the residual is
// per-node launch/serialization gaps. These three kernels are mutually
// independent elementwise/small-compute stages: merge into one launch.
// Block 0 additionally zeroes d_out (replaces the hipMemsetAsync node; k_crf
// runs strictly later in stream order).
__global__ __launch_bounds__(256) void k_pre(
    const float* __restrict__ wemb, const int* __restrict__ wx,
    const float* __restrict__ cemb, const float* __restrict__ convw,
    const float* __restrict__ convb, const int* __restrict__ cx,
    const float* __restrict__ wihF, const float* __restrict__ wihB,
    _Float16* __restrict__ x16, _Float16* __restrict__ w16,
    float* __restrict__ out) {
  int blk = blockIdx.x;
  int tid = threadIdx.x;
  if (blk == 0 && tid == 0) out[0] = 0.f;

  if (blk < NB_CONV) {
    // ---- charconv: 8 tokens/block ----
    int tok8 = tid >> 5;
    int f = tid & 31;
    int token0 = blk * CTOK;
    __shared__ float e[CTOK][LL * CDIM];
    __shared__ int ci[CTOK][LL];
    if (tid < CTOK * LL) {
      int t = tid / LL, l = tid - t * LL;
      ci[t][l] = cx[(token0 + t) * LL + l];
    }
    __syncthreads();
    for (int i = tid; i < CTOK * LL * CDIM; i += 256) {
      int t = i / (LL * CDIM);
      int r = i - t * (LL * CDIM);
      int l = r / CDIM, c = r - l * CDIM;
      e[t][l * CDIM + c] = cemb[ci[t][l] * CDIM + c];
    }
    __syncthreads();
    if (f < NFILT) {
      float d0[LL], d1[LL], d2[LL];
#pragma unroll
      for (int l = 0; l < LL; l++) { d0[l] = 0.f; d1[l] = 0.f; d2[l] = 0.f; }
      const float* et = &e[tok8][0];
      for (int c = 0; c < CDIM; c++) {
        float w0 = convw[(f * 3 + 0) * CDIM + c];
        float w1 = convw[(f * 3 + 1) * CDIM + c];
        float w2 = convw[(f * 3 + 2) * CDIM + c];
#pragma unroll
        for (int l = 0; l < LL; l++) {
          float ev = et[l * CDIM + c];
          d0[l] += ev * w0; d1[l] += ev * w1; d2[l] += ev * w2;
        }
      }
      float bias = convb[f];
      float m = -3.0e38f;
#pragma unroll
      for (int h = 0; h < LL + 2; h++) {
        float acc = bias;
        int j0 = h - 2, j1 = h - 1, j2 = h;
        if (j0 >= 0 && j0 < LL) acc += d0[j0];
        if (j1 >= 0 && j1 < LL) acc += d1[j1];
        if (j2 >= 0 && j2 < LL) acc += d2[j2];
        m = fmaxf(m, acc);
      }
      x16[(size_t)(token0 + tok8) * KPAD + WDIM + f] = (_Float16)m;
    }
  } else if (blk < NB_CONV + NB_WORD) {
    // ---- word gather -> x16[:, 0:100], zero pad [130:160) ----
    int idx = (blk - NB_CONV) * 256 + tid;
    int token = idx / KPAD;
    int d = idx - token * KPAD;
    if (d < WDIM) {
      x16[idx] = (_Float16)wemb[(size_t)wx[token] * WDIM + d];
    } else if (d >= KIN) {
      x16[idx] = (_Float16)0.f;
    }
  } else {
    // ---- wcvt: W -> f16 [832][160], padded zeros ----
    int idx = (blk - NB_CONV - NB_WORD) * 256 + tid;
    int n = idx / KPAD;
    int k = idx - n * KPAD;
    float v = 0.f;
    if (k < KIN && n < 2 * GDIM) {
      v = (n < GDIM) ? wihF[(size_t)n * KIN + k] : wihB[(size_t)(n - GDIM) * KIN + k];
    }
    w16[idx] = (_Float16)v;
  }
}

// ---------------- K2: pre = x @ wih^T + (bih+bhh), MFMA f16, f16 output ----------------
__global__ __launch_bounds__(256) void k_pregemm(
    const _Float16* __restrict__ x16, const _Float16* __restrict__ w16,
    const float* __restrict__ bihF, const float* __restrict__ bhhF,
    const float* __restrict__ bihB, const float* __restrict__ bhhB,
    _Float16* __restrict__ preF, _Float16* __restrict__ preB) {
  __shared__ __align__(16) _Float16 Asl[64 * 40];
  __shared__ __align__(16) _Float16 Bsl[64 * 40];
  int m0 = blockIdx.x * 64;
  int n0 = blockIdx.y * 64;
  int tid = threadIdx.x;
  int lane = tid & 63, w = tid >> 6;
  int quad = lane >> 4, l15 = lane & 15;

  f32x4 acc[4];
#pragma unroll
  for (int i = 0; i < 4; i++) acc[i] = (f32x4){0.f, 0.f, 0.f, 0.f};

  int r = tid >> 2;            // staging row 0..63
  int kk = (tid & 3) * 8;      // k offset within chunk
  const _Float16* xs = x16 + (size_t)(m0 + r) * KPAD + kk;
  const _Float16* wsrc = w16 + (size_t)(n0 + r) * KPAD + kk;

  for (int kc = 0; kc < 5; kc++) {
    if (kc) __syncthreads();
    *(f16x8*)&Asl[r * 40 + kk] = *(const f16x8*)(xs + kc * 32);
    *(f16x8*)&Bsl[r * 40 + kk] = *(const f16x8*)(wsrc + kc * 32);
    __syncthreads();

    f16x8 bfrag = *(const f16x8*)&Bsl[(w * 16 + l15) * 40 + quad * 8];
#pragma unroll
    for (int mt = 0; mt < 4; mt++) {
      f16x8 afrag = *(const f16x8*)&Asl[(mt * 16 + l15) * 40 + quad * 8];
      acc[mt] = __builtin_amdgcn_mfma_f32_16x16x32_f16(afrag, bfrag, acc[mt], 0, 0, 0);
    }
  }

  int ng = n0 + w * 16 + l15;  // this lane's output column (fixed)
  if (ng < 2 * GDIM) {
    int dir = ng >= GDIM;
    int jb = dir ? ng - GDIM : ng;
    _Float16* dst = dir ? preB : preF;
    float bias = (dir ? bihB : bihF)[jb] + (dir ? bhhB : bhhF)[jb];
#pragma unroll
    for (int mt = 0; mt < 4; mt++) {
#pragma unroll
      for (int i = 0; i < 4; i++) {
        int m = m0 + mt * 16 + quad * 4 + i;
        dst[(size_t)m * GDIM + jb] = (_Float16)(acc[mt][i] + bias);
      }
    }
  }
}

// ---------------- K3: recurrent LSTM scan (R15-proven, byte-identical) ----------------
__global__ __launch_bounds__(448) void k_lstm(
    const _Float16* __restrict__ preF, const _Float16* __restrict__ preB,
    const float* __restrict__ whhF, const float* __restrict__ whhB,
    _Float16* __restrict__ hbuf) {
  int blk = blockIdx.x;
  int dir = blk >> 7;   // 0 fwd, 1 bwd
  int b = blk & 127;
  const _Float16* pre = dir ? preB : preF;
  const float* whh = dir ? whhB : whhF;
  int tid = threadIdx.x;
  int kg = tid / 112;                  // 0..3
  int rg = tid - kg * 112;
  bool act = (kg < 4) && (rg < 100);
  int r0 = act ? rg * 4 : 0;           // first of 4 consecutive rows
  int kb = (act ? kg : 0) * 32;        // k-window base (halves)

  __half2 wp[4][8];
  {
#pragma unroll
    for (int i = 0; i < 4; i++) {
      const float* wr = whh + (size_t)(r0 + i) * HDIM;
#pragma unroll
      for (int q = 0; q < 8; q++) {
        int k0 = kb + 2 * q;
        float w0 = (k0 < HDIM) ? wr[k0] : 0.f;
        float w1 = (k0 + 1 < HDIM) ? wr[k0 + 1] : 0.f;
        wp[i][q] = __floats2half2_rn(w0, w1);
      }
    }
  }

  __shared__ __align__(16) _Float16 hsh16[2][128];
  __shared__ __align__(16) float gpart[4][GDIM];
  if (tid < 128) { hsh16[0][tid] = (_Float16)0.f; hsh16[1][tid] = (_Float16)0.f; }
  float c = 0.f;

  const _Float16* pbase = pre + ((size_t)b * SS + (dir ? (SS - 1) : 0)) * GDIM + r0;
  const intptr_t pstep = dir ? -(intptr_t)GDIM : (intptr_t)GDIM;
  uint2 p0 = {0, 0}, p1 = {0, 0};
  if (act && kg == 0) {
    p0 = *(const uint2*)pbase;
    p1 = *(const uint2*)(pbase + pstep);
  }
  __syncthreads();

  int cur = 0;
  for (int step = 0; step < SS; step++) {
    uint2 p2 = {0, 0};
    if (act && kg == 0) {
      int tn = (step + 2 < SS) ? (step + 2) : (SS - 1);
      p2 = *(const uint2*)(pbase + (intptr_t)tn * pstep);
    }

    if (act) {
      const uint4* h4 = (const uint4*)&hsh16[cur][kb];
      uint4 hv0 = h4[0], hv1 = h4[1];
      __half2 hp[8];
      hp[0] = __builtin_bit_cast(__half2, hv0.x);
      hp[1] = __builtin_bit_cast(__half2, hv0.y);
      hp[2] = __builtin_bit_cast(__half2, hv0.z);
      hp[3] = __builtin_bit_cast(__half2, hv0.w);
      hp[4] = __builtin_bit_cast(__half2, hv1.x);
      hp[5] = __builtin_bit_cast(__half2, hv1.y);
      hp[6] = __builtin_bit_cast(__half2, hv1.z);
      hp[7] = __builtin_bit_cast(__half2, hv1.w);

      float racc[4];
      __half2 z = __floats2half2_rn(0.f, 0.f);
#pragma unroll
      for (int i = 0; i < 4; i++) {
        __half2 a0 = z, a1 = z;
#pragma unroll
        for (int q = 0; q < 8; q += 2) {
          a0 = __hfma2(wp[i][q], hp[q], a0);
          a1 = __hfma2(wp[i][q + 1], hp[q + 1], a1);
        }
        racc[i] = (__low2float(a0) + __high2float(a0)) +
                  (__low2float(a1) + __high2float(a1));
      }
      if (kg == 0) {
        __half2 pa = __builtin_bit_cast(__half2, p0.x);
        __half2 pbv = __builtin_bit_cast(__half2, p0.y);
        racc[0] += __low2float(pa);
        racc[1] += __high2float(pa);
        racc[2] += __low2float(pbv);
        racc[3] += __high2float(pbv);
      }
      *(f32x4*)&gpart[kg][r0] = (f32x4){racc[0], racc[1], racc[2], racc[3]};
    }
    barrier_lds_only();
    if (tid < HDIM) {
      int j = tid;
      float gi = (gpart[0][j] + gpart[1][j]) + (gpart[2][j] + gpart[3][j]);
      float gf = (gpart[0][j + HDIM] + gpart[1][j + HDIM]) + (gpart[2][j + HDIM] + gpart[3][j + HDIM]);
      float gg = (gpart[0][j + 2 * HDIM] + gpart[1][j + 2 * HDIM]) + (gpart[2][j + 2 * HDIM] + gpart[3][j + 2 * HDIM]);
      float go = (gpart[0][j + 3 * HDIM] + gpart[1][j + 3 * HDIM]) + (gpart[2][j + 3 * HDIM] + gpart[3][j + 3 * HDIM]);
      float ig = sigm(gi), fg = sigm(gf), g2 = tanh_fast(gg), og = sigm(go);
      c = fg * c + ig * g2;
      float h = og * tanh_fast(c);
      hsh16[cur ^ 1][j] = (_Float16)h;
      int t = dir ? (SS - 1 - step) : step;
      hbuf[((size_t)b * SS + t) * (2 * HDIM) + dir * HDIM + j] = (_Float16)h;
    }
    barrier_lds_only();
    p0 = p1; p1 = p2;
    cur ^= 1;
  }
}

// ---------------- K4: emission = [h_f,h_b] @ proj_w^T + proj_b ----------------
__global__ void k_proj(const _Float16* __restrict__ hbuf, const float* __restrict__ pw,
                       const float* __restrict__ pb, float* __restrict__ em) {
  int idx = blockIdx.x * blockDim.x + threadIdx.x;  // token*32 + tag
  if (idx >= BB * SS * NTAGS) return;
  int token = idx >> 5, tag = idx & 31;
  const uint4* h4 = (const uint4*)(hbuf + (size_t)token * 2 * HDIM);
  const float* wrow = pw + (size_t)tag * 2 * HDIM;
  float acc = pb[tag];
#pragma unroll
  for (int k = 0; k < 25; k++) {
    uint4 hv = h4[k];
    h2 a = __builtin_bit_cast(h2, hv.x);
    h2 bq = __builtin_bit_cast(h2, hv.y);
    h2 cq = __builtin_bit_cast(h2, hv.z);
    h2 d = __builtin_bit_cast(h2, hv.w);
    const float4* w4 = (const float4*)(wrow + k * 8);
    float4 w0 = w4[0], w1 = w4[1];
    acc += (float)a.x * w0.x + (float)a.y * w0.y + (float)bq.x * w0.z + (float)bq.y * w0.w
         + (float)cq.x * w1.x + (float)cq.y * w1.y + (float)d.x * w1.z + (float)d.y * w1.w;
  }
  em[idx] = acc;
}

// ---------------- K5: CRF forward + gold score + loss (score fused in) ----------------
__global__ __launch_bounds__(64) void k_crf(const float* __restrict__ em,
                                            const float* __restrict__ trans,
                                            const int* __restrict__ mask,
                                            const int* __restrict__ y,
                                            float* __restrict__ out) {
  int g = threadIdx.x >> 5;
  int j = threadIdx.x & 31;
  int b = blockIdx.x * 2 + g;

  // ---- gold path score (was k_score), 32 lanes per batch ----
  float sacc = 0.f;
  for (int s = j; s < SS; s += 32) {
    int curt = y[b * SS + s];
    int prevt = (s == 0) ? TAG_START : y[b * SS + s - 1];
    float mk = (float)mask[b * SS + s];
    sacc += (em[((size_t)b * SS + s) * NTAGS + curt] + trans[prevt * NTAGS + curt]) * mk;
  }
#pragma unroll
  for (int off = 16; off > 0; off >>= 1) sacc += __shfl_down(sacc, off, 32);
  // lane j==0 of each group holds the gold score (minus END term, added below)
  float scoreYv = sacc + trans[y[b * SS + SS - 1] * NTAGS + TAG_END];

  float tcol[NTAGS];
#pragma unroll
  for (int i = 0; i < NTAGS; i++) tcol[i] = trans[i * NTAGS + j];
  float la = (j == TAG_START) ? 0.f : NEGV;
  __shared__ float lash[2][NTAGS];

  const float* emb = em + (size_t)b * SS * NTAGS + j;
  const int* mkb = mask + b * SS;
  float e0 = emb[0], e1 = emb[NTAGS];
  int m0i = mkb[0], m1i = mkb[1];

  for (int s = 0; s < SS; s++) {
    int sn = (s + 2 < SS) ? (s + 2) : (SS - 1);
    float e2 = emb[(size_t)sn * NTAGS];
    int m2i = mkb[sn];

    lash[g][j] = la;
    __syncthreads();
    float m = -3.0e38f;
#pragma unroll
    for (int i = 0; i < NTAGS; i++) m = fmaxf(m, lash[g][i] + tcol[i]);
    float sum = 0.f;
#pragma unroll
    for (int i = 0; i < NTAGS; i++) sum += __expf(lash[g][i] + tcol[i] - m);
    float la2 = m + __logf(sum) + e0;
    float mk = (float)m0i;
    la = la2 * mk + la * (1.f - mk);
    __syncthreads();
    e0 = e1; e1 = e2; m0i = m1i; m1i = m2i;
  }
  la += trans[j * NTAGS + TAG_END];
  lash[g][j] = la;
  __syncthreads();
  float m = -3.0e38f;
#pragma unroll
  for (int i = 0; i < NTAGS; i++) m = fmaxf(m, lash[g][i]);
  float sum = 0.f;
#pragma unroll
  for (int i = 0; i < NTAGS; i++) sum += __expf(lash[g][i] - m);
  float total = m + __logf(sum);
  if (j == 0) atomicAdd(out, (total - scoreYv) * (1.0f / BB));
}

extern "C" void kernel_launch(void* const* d_in, const int* in_sizes, int n_in,
                              void* d_out, int out_size, void* d_ws, size_t ws_size,
                              hipStream_t stream) {
  const float* word_emb = (const float*)d_in[0];
  const float* char_emb = (const float*)d_in[1];
  const float* conv_w   = (const float*)d_in[2];
  const float* conv_b   = (const float*)d_in[3];
  const float* wih_f    = (const float*)d_in[4];
  const float* whh_f    = (const float*)d_in[5];
  const float* bih_f    = (const float*)d_in[6];
  const float* bhh_f    = (const float*)d_in[7];
  const float* wih_b    = (const float*)d_in[8];
  const float* whh_b    = (const float*)d_in[9];
  const float* bih_b    = (const float*)d_in[10];
  const float* bhh_b    = (const float*)d_in[11];
  const float* proj_w   = (const float*)d_in[12];
  const float* proj_b   = (const float*)d_in[13];
  const float* trans    = (const float*)d_in[14];
  const int* word_x     = (const int*)d_in[15];
  const int* char_x     = (const int*)d_in[16];
  const int* y          = (const int*)d_in[17];
  const int* mask       = (const int*)d_in[18];
  float* out = (float*)d_out;

  _Float16* x16   = (_Float16*)d_ws;                     // 32768*160 halves
  _Float16* w16   = x16 + (size_t)BB * SS * KPAD;        // 832*160 halves
  _Float16* preF  = w16 + (size_t)NROWS * KPAD;          // 32768*400 halves
  _Float16* preB  = preF + (size_t)BB * SS * GDIM;       // 32768*400 halves
  _Float16* hbuf  = preB + (size_t)BB * SS * GDIM;       // 32768*200 halves
  float* em       = (float*)(hbuf + (size_t)BB * SS * 2 * HDIM);  // 32768*32 f32

  k_pre<<<NB_PRE, 256, 0, stream>>>(word_emb, word_x, char_emb, conv_w, conv_b,
                                    char_x, wih_f, wih_b, x16, w16, out);
  k_pregemm<<<dim3(BB * SS / 64, 13), 256, 0, stream>>>(x16, w16, bih_f, bhh_f,
                                                        bih_b, bhh_b, preF, preB);
  k_lstm<<<256, 448, 0, stream>>>(preF, preB, whh_f, whh_b, hbuf);
  k_proj<<<(BB * SS * NTAGS + 255) / 256, 256, 0, stream>>>(hbuf, proj_w, proj_b, em);
  k_crf<<<BB / 2, 64, 0, stream>>>(em, trans, mask, y, out);
}

// Round 17
// 559.863 us; speedup vs baseline: 1.4481x; 1.0516x over previous
//
#include <hip/hip_runtime.h>
#include <hip/hip_fp16.h>
#include <cstdint>
#include <cstddef>

#define BB 128
#define SS 256
#define LL 10
#define NTAGS 32
#define TAG_START 30
#define TAG_END 31
#define WDIM 100
#define CDIM 30
#define NFILT 30
#define HDIM 100
#define KIN 130      // LSTM_IN = WDIM + FILT
#define KPAD 160     // padded K for f16 GEMM operands
#define GDIM 400     // 4*H
#define NROWS 832    // 13*64 padded W rows
#define NEGV -10000.0f
#define CTOK 8       // tokens per charconv block

// fused-pre block ranges
#define NB_CONV (BB * SS / CTOK)               // 4096
#define NB_WORD (BB * SS * KPAD / 256)         // 20480
#define NB_WCVT (NROWS * KPAD / 256)           // 520
#define NB_PRE  (NB_CONV + NB_WORD + NB_WCVT)  // 25096

typedef _Float16 h2 __attribute__((ext_vector_type(2)));
typedef _Float16 f16x8 __attribute__((ext_vector_type(8)));
typedef float f32x4 __attribute__((ext_vector_type(4)));

__device__ __forceinline__ float sigm(float x) { return 1.0f / (1.0f + __expf(-x)); }
__device__ __forceinline__ float tanh_fast(float x) { return 2.0f / (1.0f + __expf(-2.0f * x)) - 1.0f; }

// lgkm-only barrier (R15-proven): leaves global prefetch/store in flight.
__device__ __forceinline__ void barrier_lds_only() {
  asm volatile("s_waitcnt lgkmcnt(0)" ::: "memory");
  __builtin_amdgcn_s_barrier();
  asm volatile("" ::: "memory");
}

// ---------------- K1 fused: charconv | word gather | wcvt, by block range ----------------
__global__ __launch_bounds__(256) void k_pre(
    const float* __restrict__ wemb, const int* __restrict__ wx,
    const float* __restrict__ cemb, const float* __restrict__ convw,
    const float* __restrict__ convb, const int* __restrict__ cx,
    const float* __restrict__ wihF, const float* __restrict__ wihB,
    _Float16* __restrict__ x16, _Float16* __restrict__ w16,
    float* __restrict__ out) {
  int blk = blockIdx.x;
  int tid = threadIdx.x;
  if (blk == 0 && tid == 0) out[0] = 0.f;

  if (blk < NB_CONV) {
    int tok8 = tid >> 5;
    int f = tid & 31;
    int token0 = blk * CTOK;
    __shared__ float e[CTOK][LL * CDIM];
    __shared__ int ci[CTOK][LL];
    if (tid < CTOK * LL) {
      int t = tid / LL, l = tid - t * LL;
      ci[t][l] = cx[(token0 + t) * LL + l];
    }
    __syncthreads();
    for (int i = tid; i < CTOK * LL * CDIM; i += 256) {
      int t = i / (LL * CDIM);
      int r = i - t * (LL * CDIM);
      int l = r / CDIM, c = r - l * CDIM;
      e[t][l * CDIM + c] = cemb[ci[t][l] * CDIM + c];
    }
    __syncthreads();
    if (f < NFILT) {
      float d0[LL], d1[LL], d2[LL];
#pragma unroll
      for (int l = 0; l < LL; l++) { d0[l] = 0.f; d1[l] = 0.f; d2[l] = 0.f; }
      const float* et = &e[tok8][0];
      for (int c = 0; c < CDIM; c++) {
        float w0 = convw[(f * 3 + 0) * CDIM + c];
        float w1 = convw[(f * 3 + 1) * CDIM + c];
        float w2 = convw[(f * 3 + 2) * CDIM + c];
#pragma unroll
        for (int l = 0; l < LL; l++) {
          float ev = et[l * CDIM + c];
          d0[l] += ev * w0; d1[l] += ev * w1; d2[l] += ev * w2;
        }
      }
      float bias = convb[f];
      float m = -3.0e38f;
#pragma unroll
      for (int h = 0; h < LL + 2; h++) {
        float acc = bias;
        int j0 = h - 2, j1 = h - 1, j2 = h;
        if (j0 >= 0 && j0 < LL) acc += d0[j0];
        if (j1 >= 0 && j1 < LL) acc += d1[j1];
        if (j2 >= 0 && j2 < LL) acc += d2[j2];
        m = fmaxf(m, acc);
      }
      x16[(size_t)(token0 + tok8) * KPAD + WDIM + f] = (_Float16)m;
    }
  } else if (blk < NB_CONV + NB_WORD) {
    int idx = (blk - NB_CONV) * 256 + tid;
    int token = idx / KPAD;
    int d = idx - token * KPAD;
    if (d < WDIM) {
      x16[idx] = (_Float16)wemb[(size_t)wx[token] * WDIM + d];
    } else if (d >= KIN) {
      x16[idx] = (_Float16)0.f;
    }
  } else {
    int idx = (blk - NB_CONV - NB_WORD) * 256 + tid;
    int n = idx / KPAD;
    int k = idx - n * KPAD;
    float v = 0.f;
    if (k < KIN && n < 2 * GDIM) {
      v = (n < GDIM) ? wihF[(size_t)n * KIN + k] : wihB[(size_t)(n - GDIM) * KIN + k];
    }
    w16[idx] = (_Float16)v;
  }
}

// ---------------- K2: pre = x @ wih^T + (bih+bhh), MFMA f16, f16 output ----------------
__global__ __launch_bounds__(256) void k_pregemm(
    const _Float16* __restrict__ x16, const _Float16* __restrict__ w16,
    const float* __restrict__ bihF, const float* __restrict__ bhhF,
    const float* __restrict__ bihB, const float* __restrict__ bhhB,
    _Float16* __restrict__ preF, _Float16* __restrict__ preB) {
  __shared__ __align__(16) _Float16 Asl[64 * 40];
  __shared__ __align__(16) _Float16 Bsl[64 * 40];
  int m0 = blockIdx.x * 64;
  int n0 = blockIdx.y * 64;
  int tid = threadIdx.x;
  int lane = tid & 63, w = tid >> 6;
  int quad = lane >> 4, l15 = lane & 15;

  f32x4 acc[4];
#pragma unroll
  for (int i = 0; i < 4; i++) acc[i] = (f32x4){0.f, 0.f, 0.f, 0.f};

  int r = tid >> 2;            // staging row 0..63
  int kk = (tid & 3) * 8;      // k offset within chunk
  const _Float16* xs = x16 + (size_t)(m0 + r) * KPAD + kk;
  const _Float16* wsrc = w16 + (size_t)(n0 + r) * KPAD + kk;

  for (int kc = 0; kc < 5; kc++) {
    if (kc) __syncthreads();
    *(f16x8*)&Asl[r * 40 + kk] = *(const f16x8*)(xs + kc * 32);
    *(f16x8*)&Bsl[r * 40 + kk] = *(const f16x8*)(wsrc + kc * 32);
    __syncthreads();

    f16x8 bfrag = *(const f16x8*)&Bsl[(w * 16 + l15) * 40 + quad * 8];
#pragma unroll
    for (int mt = 0; mt < 4; mt++) {
      f16x8 afrag = *(const f16x8*)&Asl[(mt * 16 + l15) * 40 + quad * 8];
      acc[mt] = __builtin_amdgcn_mfma_f32_16x16x32_f16(afrag, bfrag, acc[mt], 0, 0, 0);
    }
  }

  int ng = n0 + w * 16 + l15;  // this lane's output column (fixed)
  if (ng < 2 * GDIM) {
    int dir = ng >= GDIM;
    int jb = dir ? ng - GDIM : ng;
    _Float16* dst = dir ? preB : preF;
    float bias = (dir ? bihB : bihF)[jb] + (dir ? bhhB : bhhF)[jb];
#pragma unroll
    for (int mt = 0; mt < 4; mt++) {
#pragma unroll
      for (int i = 0; i < 4; i++) {
        int m = m0 + mt * 16 + quad * 4 + i;
        dst[(size_t)m * GDIM + jb] = (_Float16)(acc[mt][i] + bias);
      }
    }
  }
}

// ---------------- K3: recurrent LSTM scan (R15-proven, byte-identical) ----------------
__global__ __launch_bounds__(448) void k_lstm(
    const _Float16* __restrict__ preF, const _Float16* __restrict__ preB,
    const float* __restrict__ whhF, const float* __restrict__ whhB,
    _Float16* __restrict__ hbuf) {
  int blk = blockIdx.x;
  int dir = blk >> 7;   // 0 fwd, 1 bwd
  int b = blk & 127;
  const _Float16* pre = dir ? preB : preF;
  const float* whh = dir ? whhB : whhF;
  int tid = threadIdx.x;
  int kg = tid / 112;                  // 0..3
  int rg = tid - kg * 112;
  bool act = (kg < 4) && (rg < 100);
  int r0 = act ? rg * 4 : 0;           // first of 4 consecutive rows
  int kb = (act ? kg : 0) * 32;        // k-window base (halves)

  __half2 wp[4][8];
  {
#pragma unroll
    for (int i = 0; i < 4; i++) {
      const float* wr = whh + (size_t)(r0 + i) * HDIM;
#pragma unroll
      for (int q = 0; q < 8; q++) {
        int k0 = kb + 2 * q;
        float w0 = (k0 < HDIM) ? wr[k0] : 0.f;
        float w1 = (k0 + 1 < HDIM) ? wr[k0 + 1] : 0.f;
        wp[i][q] = __floats2half2_rn(w0, w1);
      }
    }
  }

  __shared__ __align__(16) _Float16 hsh16[2][128];
  __shared__ __align__(16) float gpart[4][GDIM];
  if (tid < 128) { hsh16[0][tid] = (_Float16)0.f; hsh16[1][tid] = (_Float16)0.f; }
  float c = 0.f;

  const _Float16* pbase = pre + ((size_t)b * SS + (dir ? (SS - 1) : 0)) * GDIM + r0;
  const intptr_t pstep = dir ? -(intptr_t)GDIM : (intptr_t)GDIM;
  uint2 p0 = {0, 0}, p1 = {0, 0};
  if (act && kg == 0) {
    p0 = *(const uint2*)pbase;
    p1 = *(const uint2*)(pbase + pstep);
  }
  __syncthreads();

  int cur = 0;
  for (int step = 0; step < SS; step++) {
    uint2 p2 = {0, 0};
    if (act && kg == 0) {
      int tn = (step + 2 < SS) ? (step + 2) : (SS - 1);
      p2 = *(const uint2*)(pbase + (intptr_t)tn * pstep);
    }

    if (act) {
      const uint4* h4 = (const uint4*)&hsh16[cur][kb];
      uint4 hv0 = h4[0], hv1 = h4[1];
      __half2 hp[8];
      hp[0] = __builtin_bit_cast(__half2, hv0.x);
      hp[1] = __builtin_bit_cast(__half2, hv0.y);
      hp[2] = __builtin_bit_cast(__half2, hv0.z);
      hp[3] = __builtin_bit_cast(__half2, hv0.w);
      hp[4] = __builtin_bit_cast(__half2, hv1.x);
      hp[5] = __builtin_bit_cast(__half2, hv1.y);
      hp[6] = __builtin_bit_cast(__half2, hv1.z);
      hp[7] = __builtin_bit_cast(__half2, hv1.w);

      float racc[4];
      __half2 z = __floats2half2_rn(0.f, 0.f);
#pragma unroll
      for (int i = 0; i < 4; i++) {
        __half2 a0 = z, a1 = z;
#pragma unroll
        for (int q = 0; q < 8; q += 2) {
          a0 = __hfma2(wp[i][q], hp[q], a0);
          a1 = __hfma2(wp[i][q + 1], hp[q + 1], a1);
        }
        racc[i] = (__low2float(a0) + __high2float(a0)) +
                  (__low2float(a1) + __high2float(a1));
      }
      if (kg == 0) {
        __half2 pa = __builtin_bit_cast(__half2, p0.x);
        __half2 pbv = __builtin_bit_cast(__half2, p0.y);
        racc[0] += __low2float(pa);
        racc[1] += __high2float(pa);
        racc[2] += __low2float(pbv);
        racc[3] += __high2float(pbv);
      }
      *(f32x4*)&gpart[kg][r0] = (f32x4){racc[0], racc[1], racc[2], racc[3]};
    }
    barrier_lds_only();
    if (tid < HDIM) {
      int j = tid;
      float gi = (gpart[0][j] + gpart[1][j]) + (gpart[2][j] + gpart[3][j]);
      float gf = (gpart[0][j + HDIM] + gpart[1][j + HDIM]) + (gpart[2][j + HDIM] + gpart[3][j + HDIM]);
      float gg = (gpart[0][j + 2 * HDIM] + gpart[1][j + 2 * HDIM]) + (gpart[2][j + 2 * HDIM] + gpart[3][j + 2 * HDIM]);
      float go = (gpart[0][j + 3 * HDIM] + gpart[1][j + 3 * HDIM]) + (gpart[2][j + 3 * HDIM] + gpart[3][j + 3 * HDIM]);
      float ig = sigm(gi), fg = sigm(gf), g2 = tanh_fast(gg), og = sigm(go);
      c = fg * c + ig * g2;
      float h = og * tanh_fast(c);
      hsh16[cur ^ 1][j] = (_Float16)h;
      int t = dir ? (SS - 1 - step) : step;
      hbuf[((size_t)b * SS + t) * (2 * HDIM) + dir * HDIM + j] = (_Float16)h;
    }
    barrier_lds_only();
    p0 = p1; p1 = p2;
    cur ^= 1;
  }
}

// ---------------- K4: emission = [h_f,h_b] @ proj_w^T + proj_b ----------------
__global__ void k_proj(const _Float16* __restrict__ hbuf, const float* __restrict__ pw,
                       const float* __restrict__ pb, float* __restrict__ em) {
  int idx = blockIdx.x * blockDim.x + threadIdx.x;  // token*32 + tag
  if (idx >= BB * SS * NTAGS) return;
  int token = idx >> 5, tag = idx & 31;
  const uint4* h4 = (const uint4*)(hbuf + (size_t)token * 2 * HDIM);
  const float* wrow = pw + (size_t)tag * 2 * HDIM;
  float acc = pb[tag];
#pragma unroll
  for (int k = 0; k < 25; k++) {
    uint4 hv = h4[k];
    h2 a = __builtin_bit_cast(h2, hv.x);
    h2 bq = __builtin_bit_cast(h2, hv.y);
    h2 cq = __builtin_bit_cast(h2, hv.z);
    h2 d = __builtin_bit_cast(h2, hv.w);
    const float4* w4 = (const float4*)(wrow + k * 8);
    float4 w0 = w4[0], w1 = w4[1];
    acc += (float)a.x * w0.x + (float)a.y * w0.y + (float)bq.x * w0.z + (float)bq.y * w0.w
         + (float)cq.x * w1.x + (float)cq.y * w1.y + (float)d.x * w1.z + (float)d.y * w1.w;
  }
  em[idx] = acc;
}

// ---------------- K5: CRF forward + gold score + loss, wave-synchronous ----------------
// One 64-lane wave per batch, ZERO barriers (R16's version: 64 blocks x 2
// batch-groups, 2 __syncthreads x 256 steps + 32-deep serial max/sum chains,
// 75% of CUs idle — the suspected hidden ~120+ us). lane=(h,j): j=tag column,
// h=i-half. la[j] lives in lanes (duplicated across halves); __shfl replaces
// LDS+barrier; per-lane reduction is 16 i's in 2-way-split chains (depth 8);
// halves combine via shfl_xor(32) with max-rescaled partial sums.
__global__ __launch_bounds__(64) void k_crf(const float* __restrict__ em,
                                            const float* __restrict__ trans,
                                            const int* __restrict__ mask,
                                            const int* __restrict__ y,
                                            float* __restrict__ out) {
  int b = blockIdx.x;
  int lane = threadIdx.x;
  int j = lane & 31;
  int h = lane >> 5;

  // ---- gold path score, 64 lanes ----
  float sacc = 0.f;
  for (int s = lane; s < SS; s += 64) {
    int curt = y[b * SS + s];
    int prevt = (s == 0) ? TAG_START : y[b * SS + s - 1];
    float mk = (float)mask[b * SS + s];
    sacc += (em[((size_t)b * SS + s) * NTAGS + curt] + trans[prevt * NTAGS + curt]) * mk;
  }
#pragma unroll
  for (int off = 32; off > 0; off >>= 1) sacc += __shfl_down(sacc, off);
  float scoreYv = __shfl(sacc, 0) + trans[y[b * SS + SS - 1] * NTAGS + TAG_END];

  // tcol: this lane's 16 (i, j) transition entries, i in [16h, 16h+16)
  float tcol[16];
#pragma unroll
  for (int i = 0; i < 16; i++) tcol[i] = trans[(h * 16 + i) * NTAGS + j];

  float la = (j == TAG_START) ? 0.f : NEGV;   // la[j], duplicated in both halves

  const float* emb = em + (size_t)b * SS * NTAGS + j;
  const int* mkb = mask + b * SS;
  float e0 = emb[0], e1 = emb[NTAGS];
  int m0i = mkb[0], m1i = mkb[1];

  for (int s = 0; s < SS; s++) {
    int sn = (s + 2 < SS) ? (s + 2) : (SS - 1);
    float e2 = emb[(size_t)sn * NTAGS];
    int m2i = mkb[sn];

    float v[16];
#pragma unroll
    for (int i = 0; i < 16; i++) v[i] = __shfl(la, h * 16 + i) + tcol[i];

    float ma = v[0], mb2 = v[1];
#pragma unroll
    for (int i = 2; i < 16; i += 2) { ma = fmaxf(ma, v[i]); mb2 = fmaxf(mb2, v[i + 1]); }
    float mh = fmaxf(ma, mb2);
    float m = fmaxf(mh, __shfl_xor(mh, 32));

    float sa = 0.f, sb = 0.f;
#pragma unroll
    for (int i = 0; i < 16; i += 2) { sa += __expf(v[i] - m); sb += __expf(v[i + 1] - m); }
    float sh = sa + sb;
    float sum = sh + __shfl_xor(sh, 32);

    float la2 = m + __logf(sum) + e0;
    float mk = (float)m0i;
    la = la2 * mk + la * (1.f - mk);
    e0 = e1; e1 = e2; m0i = m1i; m1i = m2i;
  }
  la += trans[j * NTAGS + TAG_END];

  // final logsumexp over the 32 tags (xor offsets <32 keep halves separate;
  // both halves hold identical la so both compute the same total)
  float mm = la;
#pragma unroll
  for (int off = 16; off > 0; off >>= 1) mm = fmaxf(mm, __shfl_xor(mm, off));
  float ss = __expf(la - mm);
#pragma unroll
  for (int off = 16; off > 0; off >>= 1) ss += __shfl_xor(ss, off);
  float total = mm + __logf(ss);
  if (lane == 0) atomicAdd(out, (total - scoreYv) * (1.0f / BB));
}

extern "C" void kernel_launch(void* const* d_in, const int* in_sizes, int n_in,
                              void* d_out, int out_size, void* d_ws, size_t ws_size,
                              hipStream_t stream) {
  const float* word_emb = (const float*)d_in[0];
  const float* char_emb = (const float*)d_in[1];
  const float* conv_w   = (const float*)d_in[2];
  const float* conv_b   = (const float*)d_in[3];
  const float* wih_f    = (const float*)d_in[4];
  const float* whh_f    = (const float*)d_in[5];
  const float* bih_f    = (const float*)d_in[6];
  const float* bhh_f    = (const float*)d_in[7];
  const float* wih_b    = (const float*)d_in[8];
  const float* whh_b    = (const float*)d_in[9];
  const float* bih_b    = (const float*)d_in[10];
  const float* bhh_b    = (const float*)d_in[11];
  const float* proj_w   = (const float*)d_in[12];
  const float* proj_b   = (const float*)d_in[13];
  const float* trans    = (const float*)d_in[14];
  const int* word_x     = (const int*)d_in[15];
  const int* char_x     = (const int*)d_in[16];
  const int* y          = (const int*)d_in[17];
  const int* mask       = (const int*)d_in[18];
  float* out = (float*)d_out;

  _Float16* x16   = (_Float16*)d_ws;                     // 32768*160 halves
  _Float16* w16   = x16 + (size_t)BB * SS * KPAD;        // 832*160 halves
  _Float16* preF  = w16 + (size_t)NROWS * KPAD;          // 32768*400 halves
  _Float16* preB  = preF + (size_t)BB * SS * GDIM;       // 32768*400 halves
  _Float16* hbuf  = preB + (size_t)BB * SS * GDIM;       // 32768*200 halves
  float* em       = (float*)(hbuf + (size_t)BB * SS * 2 * HDIM);  // 32768*32 f32

  k_pre<<<NB_PRE, 256, 0, stream>>>(word_emb, word_x, char_emb, conv_w, conv_b,
                                    char_x, wih_f, wih_b, x16, w16, out);
  k_pregemm<<<dim3(BB * SS / 64, 13), 256, 0, stream>>>(x16, w16, bih_f, bhh_f,
                                                        bih_b, bhh_b, preF, preB);
  k_lstm<<<256, 448, 0, stream>>>(preF, preB, whh_f, whh_b, hbuf);
  k_proj<<<(BB * SS * NTAGS + 255) / 256, 256, 0, stream>>>(hbuf, proj_w, proj_b, em);
  k_crf<<<BB, 64, 0, stream>>>(em, trans, mask, y, out);
}

// Round 18
// 545.381 us; speedup vs baseline: 1.4866x; 1.0266x over previous
//
#include <hip/hip_runtime.h>
#include <hip/hip_fp16.h>
#include <cstdint>
#include <cstddef>

#define BB 128
#define SS 256
#define LL 10
#define NTAGS 32
#define TAG_START 30
#define TAG_END 31
#define WDIM 100
#define CDIM 30
#define NFILT 30
#define HDIM 100
#define KIN 130      // LSTM_IN = WDIM + FILT
#define KPAD 160     // padded K for f16 GEMM operands
#define GDIM 400     // 4*H
#define NROWS 832    // 13*64 padded W rows
#define NEGV -10000.0f
#define CTOK 8       // tokens per charconv block

// fused-pre block ranges
#define NB_CONV (BB * SS / CTOK)               // 4096
#define NB_WORD (BB * SS * KPAD / 256)         // 20480
#define NB_WCVT (NROWS * KPAD / 256)           // 520
#define NB_PRE  (NB_CONV + NB_WORD + NB_WCVT)  // 25096

typedef _Float16 h2 __attribute__((ext_vector_type(2)));
typedef _Float16 f16x8 __attribute__((ext_vector_type(8)));
typedef float f32x4 __attribute__((ext_vector_type(4)));

__device__ __forceinline__ float sigm(float x) { return 1.0f / (1.0f + __expf(-x)); }
__device__ __forceinline__ float tanh_fast(float x) { return 2.0f / (1.0f + __expf(-2.0f * x)) - 1.0f; }

// lgkm-only barrier (R15-proven): leaves global prefetch/store in flight.
__device__ __forceinline__ void barrier_lds_only() {
  asm volatile("s_waitcnt lgkmcnt(0)" ::: "memory");
  __builtin_amdgcn_s_barrier();
  asm volatile("" ::: "memory");
}

// ---------------- K1 fused: charconv | word gather | wcvt, by block range ----------------
// R18 delta: the conv branch previously read convw straight from global with
// lane index f -> 30 distinct cache lines PER LOAD x 90 loads/thread; with
// 64 waves/CU sharing one L1 (~1 line/cyc) that's ~70 us of L1 serialization.
// convw/convb are now staged once into LDS (coalesced) and the hot loop reads
// LDS at <=2-way bank aliasing (free).
__global__ __launch_bounds__(256) void k_pre(
    const float* __restrict__ wemb, const int* __restrict__ wx,
    const float* __restrict__ cemb, const float* __restrict__ convw,
    const float* __restrict__ convb, const int* __restrict__ cx,
    const float* __restrict__ wihF, const float* __restrict__ wihB,
    _Float16* __restrict__ x16, _Float16* __restrict__ w16,
    float* __restrict__ out) {
  int blk = blockIdx.x;
  int tid = threadIdx.x;
  if (blk == 0 && tid == 0) out[0] = 0.f;

  if (blk < NB_CONV) {
    int tok8 = tid >> 5;
    int f = tid & 31;
    int token0 = blk * CTOK;
    __shared__ float e[CTOK][LL * CDIM];
    __shared__ float cw[NFILT * 3 * CDIM];   // 2700 floats = 10.8 KB
    __shared__ float cb[NFILT];
    __shared__ int ci[CTOK][LL];
    if (tid < CTOK * LL) {
      int t = tid / LL, l = tid - t * LL;
      ci[t][l] = cx[(token0 + t) * LL + l];
    }
    for (int i = tid; i < NFILT * 3 * CDIM; i += 256) cw[i] = convw[i];
    if (tid < NFILT) cb[tid] = convb[tid];
    __syncthreads();
    for (int i = tid; i < CTOK * LL * CDIM; i += 256) {
      int t = i / (LL * CDIM);
      int r = i - t * (LL * CDIM);
      int l = r / CDIM, c = r - l * CDIM;
      e[t][l * CDIM + c] = cemb[ci[t][l] * CDIM + c];
    }
    __syncthreads();
    if (f < NFILT) {
      float d0[LL], d1[LL], d2[LL];
#pragma unroll
      for (int l = 0; l < LL; l++) { d0[l] = 0.f; d1[l] = 0.f; d2[l] = 0.f; }
      const float* et = &e[tok8][0];
      for (int c = 0; c < CDIM; c++) {
        float w0 = cw[(f * 3 + 0) * CDIM + c];
        float w1 = cw[(f * 3 + 1) * CDIM + c];
        float w2 = cw[(f * 3 + 2) * CDIM + c];
#pragma unroll
        for (int l = 0; l < LL; l++) {
          float ev = et[l * CDIM + c];
          d0[l] += ev * w0; d1[l] += ev * w1; d2[l] += ev * w2;
        }
      }
      float bias = cb[f];
      float m = -3.0e38f;
#pragma unroll
      for (int h = 0; h < LL + 2; h++) {
        float acc = bias;
        int j0 = h - 2, j1 = h - 1, j2 = h;
        if (j0 >= 0 && j0 < LL) acc += d0[j0];
        if (j1 >= 0 && j1 < LL) acc += d1[j1];
        if (j2 >= 0 && j2 < LL) acc += d2[j2];
        m = fmaxf(m, acc);
      }
      x16[(size_t)(token0 + tok8) * KPAD + WDIM + f] = (_Float16)m;
    }
  } else if (blk < NB_CONV + NB_WORD) {
    int idx = (blk - NB_CONV) * 256 + tid;
    int token = idx / KPAD;
    int d = idx - token * KPAD;
    if (d < WDIM) {
      x16[idx] = (_Float16)wemb[(size_t)wx[token] * WDIM + d];
    } else if (d >= KIN) {
      x16[idx] = (_Float16)0.f;
    }
  } else {
    int idx = (blk - NB_CONV - NB_WORD) * 256 + tid;
    int n = idx / KPAD;
    int k = idx - n * KPAD;
    float v = 0.f;
    if (k < KIN && n < 2 * GDIM) {
      v = (n < GDIM) ? wihF[(size_t)n * KIN + k] : wihB[(size_t)(n - GDIM) * KIN + k];
    }
    w16[idx] = (_Float16)v;
  }
}

// ---------------- K2: pre = x @ wih^T + (bih+bhh), MFMA f16, f16 output ----------------
__global__ __launch_bounds__(256) void k_pregemm(
    const _Float16* __restrict__ x16, const _Float16* __restrict__ w16,
    const float* __restrict__ bihF, const float* __restrict__ bhhF,
    const float* __restrict__ bihB, const float* __restrict__ bhhB,
    _Float16* __restrict__ preF, _Float16* __restrict__ preB) {
  __shared__ __align__(16) _Float16 Asl[64 * 40];
  __shared__ __align__(16) _Float16 Bsl[64 * 40];
  int m0 = blockIdx.x * 64;
  int n0 = blockIdx.y * 64;
  int tid = threadIdx.x;
  int lane = tid & 63, w = tid >> 6;
  int quad = lane >> 4, l15 = lane & 15;

  f32x4 acc[4];
#pragma unroll
  for (int i = 0; i < 4; i++) acc[i] = (f32x4){0.f, 0.f, 0.f, 0.f};

  int r = tid >> 2;            // staging row 0..63
  int kk = (tid & 3) * 8;      // k offset within chunk
  const _Float16* xs = x16 + (size_t)(m0 + r) * KPAD + kk;
  const _Float16* wsrc = w16 + (size_t)(n0 + r) * KPAD + kk;

  for (int kc = 0; kc < 5; kc++) {
    if (kc) __syncthreads();
    *(f16x8*)&Asl[r * 40 + kk] = *(const f16x8*)(xs + kc * 32);
    *(f16x8*)&Bsl[r * 40 + kk] = *(const f16x8*)(wsrc + kc * 32);
    __syncthreads();

    f16x8 bfrag = *(const f16x8*)&Bsl[(w * 16 + l15) * 40 + quad * 8];
#pragma unroll
    for (int mt = 0; mt < 4; mt++) {
      f16x8 afrag = *(const f16x8*)&Asl[(mt * 16 + l15) * 40 + quad * 8];
      acc[mt] = __builtin_amdgcn_mfma_f32_16x16x32_f16(afrag, bfrag, acc[mt], 0, 0, 0);
    }
  }

  int ng = n0 + w * 16 + l15;  // this lane's output column (fixed)
  if (ng < 2 * GDIM) {
    int dir = ng >= GDIM;
    int jb = dir ? ng - GDIM : ng;
    _Float16* dst = dir ? preB : preF;
    float bias = (dir ? bihB : bihF)[jb] + (dir ? bhhB : bhhF)[jb];
#pragma unroll
    for (int mt = 0; mt < 4; mt++) {
#pragma unroll
      for (int i = 0; i < 4; i++) {
        int m = m0 + mt * 16 + quad * 4 + i;
        dst[(size_t)m * GDIM + jb] = (_Float16)(acc[mt][i] + bias);
      }
    }
  }
}

// ---------------- K3: recurrent LSTM scan (R15-proven, byte-identical) ----------------
__global__ __launch_bounds__(448) void k_lstm(
    const _Float16* __restrict__ preF, const _Float16* __restrict__ preB,
    const float* __restrict__ whhF, const float* __restrict__ whhB,
    _Float16* __restrict__ hbuf) {
  int blk = blockIdx.x;
  int dir = blk >> 7;   // 0 fwd, 1 bwd
  int b = blk & 127;
  const _Float16* pre = dir ? preB : preF;
  const float* whh = dir ? whhB : whhF;
  int tid = threadIdx.x;
  int kg = tid / 112;                  // 0..3
  int rg = tid - kg * 112;
  bool act = (kg < 4) && (rg < 100);
  int r0 = act ? rg * 4 : 0;           // first of 4 consecutive rows
  int kb = (act ? kg : 0) * 32;        // k-window base (halves)

  __half2 wp[4][8];
  {
#pragma unroll
    for (int i = 0; i < 4; i++) {
      const float* wr = whh + (size_t)(r0 + i) * HDIM;
#pragma unroll
      for (int q = 0; q < 8; q++) {
        int k0 = kb + 2 * q;
        float w0 = (k0 < HDIM) ? wr[k0] : 0.f;
        float w1 = (k0 + 1 < HDIM) ? wr[k0 + 1] : 0.f;
        wp[i][q] = __floats2half2_rn(w0, w1);
      }
    }
  }

  __shared__ __align__(16) _Float16 hsh16[2][128];
  __shared__ __align__(16) float gpart[4][GDIM];
  if (tid < 128) { hsh16[0][tid] = (_Float16)0.f; hsh16[1][tid] = (_Float16)0.f; }
  float c = 0.f;

  const _Float16* pbase = pre + ((size_t)b * SS + (dir ? (SS - 1) : 0)) * GDIM + r0;
  const intptr_t pstep = dir ? -(intptr_t)GDIM : (intptr_t)GDIM;
  uint2 p0 = {0, 0}, p1 = {0, 0};
  if (act && kg == 0) {
    p0 = *(const uint2*)pbase;
    p1 = *(const uint2*)(pbase + pstep);
  }
  __syncthreads();

  int cur = 0;
  for (int step = 0; step < SS; step++) {
    uint2 p2 = {0, 0};
    if (act && kg == 0) {
      int tn = (step + 2 < SS) ? (step + 2) : (SS - 1);
      p2 = *(const uint2*)(pbase + (intptr_t)tn * pstep);
    }

    if (act) {
      const uint4* h4 = (const uint4*)&hsh16[cur][kb];
      uint4 hv0 = h4[0], hv1 = h4[1];
      __half2 hp[8];
      hp[0] = __builtin_bit_cast(__half2, hv0.x);
      hp[1] = __builtin_bit_cast(__half2, hv0.y);
      hp[2] = __builtin_bit_cast(__half2, hv0.z);
      hp[3] = __builtin_bit_cast(__half2, hv0.w);
      hp[4] = __builtin_bit_cast(__half2, hv1.x);
      hp[5] = __builtin_bit_cast(__half2, hv1.y);
      hp[6] = __builtin_bit_cast(__half2, hv1.z);
      hp[7] = __builtin_bit_cast(__half2, hv1.w);

      float racc[4];
      __half2 z = __floats2half2_rn(0.f, 0.f);
#pragma unroll
      for (int i = 0; i < 4; i++) {
        __half2 a0 = z, a1 = z;
#pragma unroll
        for (int q = 0; q < 8; q += 2) {
          a0 = __hfma2(wp[i][q], hp[q], a0);
          a1 = __hfma2(wp[i][q + 1], hp[q + 1], a1);
        }
        racc[i] = (__low2float(a0) + __high2float(a0)) +
                  (__low2float(a1) + __high2float(a1));
      }
      if (kg == 0) {
        __half2 pa = __builtin_bit_cast(__half2, p0.x);
        __half2 pbv = __builtin_bit_cast(__half2, p0.y);
        racc[0] += __low2float(pa);
        racc[1] += __high2float(pa);
        racc[2] += __low2float(pbv);
        racc[3] += __high2float(pbv);
      }
      *(f32x4*)&gpart[kg][r0] = (f32x4){racc[0], racc[1], racc[2], racc[3]};
    }
    barrier_lds_only();
    if (tid < HDIM) {
      int j = tid;
      float gi = (gpart[0][j] + gpart[1][j]) + (gpart[2][j] + gpart[3][j]);
      float gf = (gpart[0][j + HDIM] + gpart[1][j + HDIM]) + (gpart[2][j + HDIM] + gpart[3][j + HDIM]);
      float gg = (gpart[0][j + 2 * HDIM] + gpart[1][j + 2 * HDIM]) + (gpart[2][j + 2 * HDIM] + gpart[3][j + 2 * HDIM]);
      float go = (gpart[0][j + 3 * HDIM] + gpart[1][j + 3 * HDIM]) + (gpart[2][j + 3 * HDIM] + gpart[3][j + 3 * HDIM]);
      float ig = sigm(gi), fg = sigm(gf), g2 = tanh_fast(gg), og = sigm(go);
      c = fg * c + ig * g2;
      float h = og * tanh_fast(c);
      hsh16[cur ^ 1][j] = (_Float16)h;
      int t = dir ? (SS - 1 - step) : step;
      hbuf[((size_t)b * SS + t) * (2 * HDIM) + dir * HDIM + j] = (_Float16)h;
    }
    barrier_lds_only();
    p0 = p1; p1 = p2;
    cur ^= 1;
  }
}

// ---------------- K4: emission = [h_f,h_b] @ proj_w^T + proj_b ----------------
// R18 delta: pw reads were lane-divergent (tag*200 stride -> 32 distinct L1
// lines per load x 75 loads/thread). pw+pb now staged once per block into LDS
// with padded row stride 204 (16B-aligned, conflict-free b128 reads: bank
// phase tag*12%32 -> 2-way max = free). Same values, same summation order.
__global__ __launch_bounds__(256) void k_proj(const _Float16* __restrict__ hbuf,
                                              const float* __restrict__ pw,
                                              const float* __restrict__ pb,
                                              float* __restrict__ em) {
  __shared__ __align__(16) float pws[NTAGS * 204];   // 25.9 KB
  __shared__ float pbs[NTAGS];
  int tid = threadIdx.x;
  for (int i = tid; i < NTAGS * 2 * HDIM; i += 256) {
    int tag = i / (2 * HDIM);
    int k = i - tag * (2 * HDIM);
    pws[tag * 204 + k] = pw[i];
  }
  if (tid < NTAGS) pbs[tid] = pb[tid];
  __syncthreads();

  int idx = blockIdx.x * blockDim.x + tid;  // token*32 + tag
  if (idx >= BB * SS * NTAGS) return;
  int token = idx >> 5, tag = idx & 31;
  const uint4* h4 = (const uint4*)(hbuf + (size_t)token * 2 * HDIM);
  const float4* w4 = (const float4*)&pws[tag * 204];
  float acc = pbs[tag];
#pragma unroll
  for (int k = 0; k < 25; k++) {
    uint4 hv = h4[k];
    h2 a = __builtin_bit_cast(h2, hv.x);
    h2 bq = __builtin_bit_cast(h2, hv.y);
    h2 cq = __builtin_bit_cast(h2, hv.z);
    h2 d = __builtin_bit_cast(h2, hv.w);
    float4 w0 = w4[k * 2], w1 = w4[k * 2 + 1];
    acc += (float)a.x * w0.x + (float)a.y * w0.y + (float)bq.x * w0.z + (float)bq.y * w0.w
         + (float)cq.x * w1.x + (float)cq.y * w1.y + (float)d.x * w1.z + (float)d.y * w1.w;
  }
  em[idx] = acc;
}

// ---------------- K5: CRF forward + gold score + loss, wave-synchronous ----------------
__global__ __launch_bounds__(64) void k_crf(const float* __restrict__ em,
                                            const float* __restrict__ trans,
                                            const int* __restrict__ mask,
                                            const int* __restrict__ y,
                                            float* __restrict__ out) {
  int b = blockIdx.x;
  int lane = threadIdx.x;
  int j = lane & 31;
  int h = lane >> 5;

  // ---- gold path score, 64 lanes ----
  float sacc = 0.f;
  for (int s = lane; s < SS; s += 64) {
    int curt = y[b * SS + s];
    int prevt = (s == 0) ? TAG_START : y[b * SS + s - 1];
    float mk = (float)mask[b * SS + s];
    sacc += (em[((size_t)b * SS + s) * NTAGS + curt] + trans[prevt * NTAGS + curt]) * mk;
  }
#pragma unroll
  for (int off = 32; off > 0; off >>= 1) sacc += __shfl_down(sacc, off);
  float scoreYv = __shfl(sacc, 0) + trans[y[b * SS + SS - 1] * NTAGS + TAG_END];

  float tcol[16];
#pragma unroll
  for (int i = 0; i < 16; i++) tcol[i] = trans[(h * 16 + i) * NTAGS + j];

  float la = (j == TAG_START) ? 0.f : NEGV;

  const float* emb = em + (size_t)b * SS * NTAGS + j;
  const int* mkb = mask + b * SS;
  float e0 = emb[0], e1 = emb[NTAGS];
  int m0i = mkb[0], m1i = mkb[1];

  for (int s = 0; s < SS; s++) {
    int sn = (s + 2 < SS) ? (s + 2) : (SS - 1);
    float e2 = emb[(size_t)sn * NTAGS];
    int m2i = mkb[sn];

    float v[16];
#pragma unroll
    for (int i = 0; i < 16; i++) v[i] = __shfl(la, h * 16 + i) + tcol[i];

    float ma = v[0], mb2 = v[1];
#pragma unroll
    for (int i = 2; i < 16; i += 2) { ma = fmaxf(ma, v[i]); mb2 = fmaxf(mb2, v[i + 1]); }
    float mh = fmaxf(ma, mb2);
    float m = fmaxf(mh, __shfl_xor(mh, 32));

    float sa = 0.f, sb = 0.f;
#pragma unroll
    for (int i = 0; i < 16; i += 2) { sa += __expf(v[i] - m); sb += __expf(v[i + 1] - m); }
    float sh = sa + sb;
    float sum = sh + __shfl_xor(sh, 32);

    float la2 = m + __logf(sum) + e0;
    float mk = (float)m0i;
    la = la2 * mk + la * (1.f - mk);
    e0 = e1; e1 = e2; m0i = m1i; m1i = m2i;
  }
  la += trans[j * NTAGS + TAG_END];

  float mm = la;
#pragma unroll
  for (int off = 16; off > 0; off >>= 1) mm = fmaxf(mm, __shfl_xor(mm, off));
  float ss = __expf(la - mm);
#pragma unroll
  for (int off = 16; off > 0; off >>= 1) ss += __shfl_xor(ss, off);
  float total = mm + __logf(ss);
  if (lane == 0) atomicAdd(out, (total - scoreYv) * (1.0f / BB));
}

extern "C" void kernel_launch(void* const* d_in, const int* in_sizes, int n_in,
                              void* d_out, int out_size, void* d_ws, size_t ws_size,
                              hipStream_t stream) {
  const float* word_emb = (const float*)d_in[0];
  const float* char_emb = (const float*)d_in[1];
  const float* conv_w   = (const float*)d_in[2];
  const float* conv_b   = (const float*)d_in[3];
  const float* wih_f    = (const float*)d_in[4];
  const float* whh_f    = (const float*)d_in[5];
  const float* bih_f    = (const float*)d_in[6];
  const float* bhh_f    = (const float*)d_in[7];
  const float* wih_b    = (const float*)d_in[8];
  const float* whh_b    = (const float*)d_in[9];
  const float* bih_b    = (const float*)d_in[10];
  const float* bhh_b    = (const float*)d_in[11];
  const float* proj_w   = (const float*)d_in[12];
  const float* proj_b   = (const float*)d_in[13];
  const float* trans    = (const float*)d_in[14];
  const int* word_x     = (const int*)d_in[15];
  const int* char_x     = (const int*)d_in[16];
  const int* y          = (const int*)d_in[17];
  const int* mask       = (const int*)d_in[18];
  float* out = (float*)d_out;

  _Float16* x16   = (_Float16*)d_ws;                     // 32768*160 halves
  _Float16* w16   = x16 + (size_t)BB * SS * KPAD;        // 832*160 halves
  _Float16* preF  = w16 + (size_t)NROWS * KPAD;          // 32768*400 halves
  _Float16* preB  = preF + (size_t)BB * SS * GDIM;       // 32768*400 halves
  _Float16* hbuf  = preB + (size_t)BB * SS * GDIM;       // 32768*200 halves
  float* em       = (float*)(hbuf + (size_t)BB * SS * 2 * HDIM);  // 32768*32 f32

  k_pre<<<NB_PRE, 256, 0, stream>>>(word_emb, word_x, char_emb, conv_w, conv_b,
                                    char_x, wih_f, wih_b, x16, w16, out);
  k_pregemm<<<dim3(BB * SS / 64, 13), 256, 0, stream>>>(x16, w16, bih_f, bhh_f,
                                                        bih_b, bhh_b, preF, preB);
  k_lstm<<<256, 448, 0, stream>>>(preF, preB, whh_f, whh_b, hbuf);
  k_proj<<<(BB * SS * NTAGS + 255) / 256, 256, 0, stream>>>(hbuf, proj_w, proj_b, em);
  k_crf<<<BB, 64, 0, stream>>>(em, trans, mask, y, out);
}